// Round 2
// baseline (1866.446 us; speedup 1.0000x reference)
//
#include <hip/hip_runtime.h>
#include <hip/hip_bf16.h>

// Problem constants (from reference)
#define N_NODES 50000
#define N_EDGES 10000
#define NNZV    250000
#define IN_CH   128
#define HDIM    64
#define DSTALK  6
#define HD      384   // HDIM * DSTALK
#define NROWS   (N_NODES * DSTALK)   // 300000
#define EROWS   (N_EDGES * DSTALK)   // 60000

// ---------------------------------------------------------------------------
// W-prep 1: W0eff[k][j=r*64+h] = sum_m W_lin[k][r*64+m] * W0[m][h]
// (fuses input projection with conv0's weight: xs@W0 == x@W0eff + c0)
__global__ __launch_bounds__(256) void k_weff(
    const float* __restrict__ W_lin, const float* __restrict__ W0,
    float* __restrict__ W0eff) {
  int idx = blockIdx.x * blockDim.x + threadIdx.x;
  if (idx >= IN_CH * HD) return;
  int k = idx / HD, j = idx - k * HD;
  int r = j >> 6, h = j & 63;
  float s = 0.f;
#pragma unroll 8
  for (int m = 0; m < HDIM; m++)
    s += W_lin[k * HD + r * HDIM + m] * W0[m * HDIM + h];
  W0eff[idx] = s;
}

// W-prep 2: Wm (stalk-mean of W_lin), cm (stalk-mean of b_lin),
//           c0[j] = sum_m b_lin[r*64+m] * W0[m][h]
__global__ __launch_bounds__(256) void k_wsmall(
    const float* __restrict__ W_lin, const float* __restrict__ b_lin,
    const float* __restrict__ W0,
    float* __restrict__ Wm, float* __restrict__ cm, float* __restrict__ c0) {
  int idx = blockIdx.x * blockDim.x + threadIdx.x;
  if (idx < IN_CH * HDIM) {            // Wm
    int k = idx >> 6, h = idx & 63;
    float s = 0.f;
#pragma unroll
    for (int r = 0; r < DSTALK; r++) s += W_lin[k * HD + r * HDIM + h];
    Wm[idx] = s * (1.f / 6.f);
  } else if (idx < IN_CH * HDIM + HD) {  // c0
    int j = idx - IN_CH * HDIM;
    int r = j >> 6, h = j & 63;
    float s = 0.f;
#pragma unroll 8
    for (int m = 0; m < HDIM; m++) s += b_lin[r * HDIM + m] * W0[m * HDIM + h];
    c0[j] = s;
  } else if (idx < IN_CH * HDIM + HD + HDIM) {  // cm
    int h = idx - IN_CH * HDIM - HD;
    float s = 0.f;
#pragma unroll
    for (int r = 0; r < DSTALK; r++) s += b_lin[r * HDIM + h];
    cm[h] = s * (1.f / 6.f);
  }
}

// ---------------------------------------------------------------------------
// xa[row][h] = sum_k in[row][k] * Wm[k][h] + cm[h]; rows 0..N-1 nodes, then edges
__global__ __launch_bounds__(256) void k_xa(
    const float* __restrict__ x, const float* __restrict__ ea,
    const float* __restrict__ Wm, const float* __restrict__ cm,
    float* __restrict__ xa) {
  __shared__ float lx[64][IN_CH];
  const int row0 = blockIdx.x * 64;
  const int tid = threadIdx.x;
  for (int i = tid; i < 64 * IN_CH; i += 256) {
    int r = i >> 7, k = i & 127;
    int row = row0 + r;
    float v = 0.f;
    if (row < N_NODES) v = x[row * IN_CH + k];
    else if (row < N_NODES + N_EDGES) v = ea[(row - N_NODES) * IN_CH + k];
    lx[r][k] = v;
  }
  __syncthreads();
  const int col = tid & 63, rg = tid >> 6;  // 4 groups x 16 rows
  float acc[16];
#pragma unroll
  for (int i = 0; i < 16; i++) acc[i] = 0.f;
  for (int k = 0; k < IN_CH; k++) {
    float w = Wm[k * HDIM + col];
#pragma unroll
    for (int i = 0; i < 16; i++) acc[i] += lx[rg * 16 + i][k] * w;
  }
  float c = cm[col];
#pragma unroll
  for (int i = 0; i < 16; i++) {
    int row = row0 + rg * 16 + i;
    if (row < N_NODES + N_EDGES) xa[row * HDIM + col] = acc[i] + c;
  }
}

// ---------------------------------------------------------------------------
// xl0[n*384 + j] = sum_k x[n][k] * W0eff[k][j] + c0[j]   (this IS xs@W0, [N*D x 64])
__global__ __launch_bounds__(384) void k_xl0(
    const float* __restrict__ x, const float* __restrict__ W0eff,
    const float* __restrict__ c0, float* __restrict__ xl0) {
  __shared__ float lx[16][IN_CH];
  const int row0 = blockIdx.x * 16;
  const int tid = threadIdx.x;
  for (int i = tid; i < 16 * IN_CH; i += 384) {
    int r = i >> 7, k = i & 127;
    int row = row0 + r;
    lx[r][k] = (row < N_NODES) ? x[row * IN_CH + k] : 0.f;
  }
  __syncthreads();
  const int j = tid;  // 0..383
  float acc[16];
#pragma unroll
  for (int r = 0; r < 16; r++) acc[r] = 0.f;
  for (int k = 0; k < IN_CH; k++) {
    float w = W0eff[k * HD + j];
#pragma unroll
    for (int r = 0; r < 16; r++) acc[r] += lx[r][k] * w;
  }
  const float bb = c0[j];
#pragma unroll
  for (int r = 0; r < 16; r++) {
    int row = row0 + r;
    if (row < N_NODES) xl0[(size_t)row * HD + j] = acc[r] + bb;
  }
}

// ---------------------------------------------------------------------------
// per-incidence LayerNorm(128) + W_sheaf + sigmoid -> alpha [NNZ x 6]
__global__ __launch_bounds__(256) void k_sheaf(
    const float* __restrict__ xa, const float* __restrict__ eam,
    const int* __restrict__ nidx, const int* __restrict__ eidx,
    const float* __restrict__ g, const float* __restrict__ bln,
    const float* __restrict__ Ws, const float* __restrict__ bs,
    float* __restrict__ alpha) {
  int w = (blockIdx.x * blockDim.x + threadIdx.x) >> 6;
  int lane = threadIdx.x & 63;
  if (w >= NNZV) return;
  int n = nidx[w], e = eidx[w];
  float f1 = xa[n * HDIM + lane];
  float f2 = eam[e * HDIM + lane];
  float s = f1 + f2;
#pragma unroll
  for (int o = 32; o; o >>= 1) s += __shfl_xor(s, o);
  float mu = s * (1.f / 128.f);
  float d1 = f1 - mu, d2 = f2 - mu;
  float v = d1 * d1 + d2 * d2;
#pragma unroll
  for (int o = 32; o; o >>= 1) v += __shfl_xor(v, o);
  float rs = rsqrtf(v * (1.f / 128.f) + 1e-5f);
  float n1 = d1 * rs * g[lane] + bln[lane];
  float n2 = d2 * rs * g[64 + lane] + bln[64 + lane];
#pragma unroll
  for (int r = 0; r < DSTALK; r++) {
    float t = n1 * Ws[lane * DSTALK + r] + n2 * Ws[(64 + lane) * DSTALK + r];
#pragma unroll
    for (int o = 32; o; o >>= 1) t += __shfl_xor(t, o);
    if (lane == 0) {
      float z = t + bs[r];
      alpha[w * DSTALK + r] = 1.f / (1.f + expf(-z));
    }
  }
}

// ---------------------------------------------------------------------------
__global__ void k_count(const int* __restrict__ nidx, const int* __restrict__ eidx,
                        int* __restrict__ cntN, int* __restrict__ cntE) {
  int j = blockIdx.x * blockDim.x + threadIdx.x;
  if (j < NNZV) {
    atomicAdd(&cntN[nidx[j]], 1);
    atomicAdd(&cntE[eidx[j]], 1);
  }
}
__global__ void k_inv(const int* __restrict__ cnt, float* __restrict__ inv, int n) {
  int i = blockIdx.x * blockDim.x + threadIdx.x;
  if (i < n) inv[i] = cnt[i] > 0 ? 1.f / (float)cnt[i] : 0.f;
}

// ---------------------------------------------------------------------------
// h1/xl GEMM for conv1: xl1 = h1 @ W1 (rows = 300000, 64x64 weight)
__global__ __launch_bounds__(256) void k_xw(const float* __restrict__ xin,
                                            const float* __restrict__ W,
                                            float* __restrict__ xl) {
  __shared__ float lw[64][64];
  __shared__ float lx[16][64];
  const int tid = threadIdx.x;
  for (int i = tid; i < 64 * 64; i += 256) lw[i >> 6][i & 63] = W[i];
  const int row0 = blockIdx.x * 16;
  for (int i = tid; i < 16 * 64; i += 256)
    lx[i >> 6][i & 63] = xin[(size_t)(row0 + (i >> 6)) * HDIM + (i & 63)];
  __syncthreads();
  const int c = tid & 63, rg = tid >> 6;
  float acc[4];
#pragma unroll
  for (int rr = 0; rr < 4; rr++) acc[rr] = 0.f;
  for (int k = 0; k < 64; k++) {
    float w = lw[k][c];
#pragma unroll
    for (int rr = 0; rr < 4; rr++) acc[rr] += lx[rg * 4 + rr][k] * w;
  }
#pragma unroll
  for (int rr = 0; rr < 4; rr++)
    xl[(size_t)(row0 + rg * 4 + rr) * HDIM + c] = acc[rr];
}

// ---------------------------------------------------------------------------
// scatter to edges: msum[e*6+r, h] += alpha[j,r] * xl[n*6+r, h]
__global__ __launch_bounds__(256) void k_scatter_e(
    const int* __restrict__ nidx, const int* __restrict__ eidx,
    const float* __restrict__ alpha, const float* __restrict__ xl,
    float* __restrict__ msum) {
  int w = (blockIdx.x * blockDim.x + threadIdx.x) >> 6;
  int lane = threadIdx.x & 63;
  if (w >= NNZV) return;
  int n = nidx[w], e = eidx[w];
#pragma unroll
  for (int r = 0; r < DSTALK; r++) {
    float a = alpha[w * DSTALK + r];
    float v = a * xl[(size_t)(n * DSTALK + r) * HDIM + lane];
    atomicAdd(&msum[(size_t)(e * DSTALK + r) * HDIM + lane], v);
  }
}

// acc = xl + bias(col)  (acc may alias xl: pure elementwise)
__global__ void k_bias(const float* __restrict__ xl, const float* __restrict__ b,
                       float* __restrict__ acc, int total) {
  int i = blockIdx.x * blockDim.x + threadIdx.x;
  if (i < total) acc[i] = xl[i] + b[i & 63];
}

// scatter back to nodes: acc[n*6+r, h] -= Dinv[n]*Binv[e]*alpha[j,r]*msum[e*6+r, h]
__global__ __launch_bounds__(256) void k_scatter_n(
    const int* __restrict__ nidx, const int* __restrict__ eidx,
    const float* __restrict__ alpha, const float* __restrict__ msum,
    const float* __restrict__ Dinv, const float* __restrict__ Binv,
    float* __restrict__ acc) {
  int w = (blockIdx.x * blockDim.x + threadIdx.x) >> 6;
  int lane = threadIdx.x & 63;
  if (w >= NNZV) return;
  int n = nidx[w], e = eidx[w];
  float scale = Dinv[n] * Binv[e];
#pragma unroll
  for (int r = 0; r < DSTALK; r++) {
    float a = alpha[w * DSTALK + r];
    float v = scale * a * msum[(size_t)(e * DSTALK + r) * HDIM + lane];
    atomicAdd(&acc[(size_t)(n * DSTALK + r) * HDIM + lane], -v);
  }
}

// in-place ELU (f32)
__global__ void k_elu(float* __restrict__ a, int total) {
  int i = blockIdx.x * blockDim.x + threadIdx.x;
  if (i < total) {
    float v = a[i];
    a[i] = v > 0.f ? v : expm1f(v);
  }
}

// ---------------------------------------------------------------------------
extern "C" void kernel_launch(void* const* d_in, const int* in_sizes, int n_in,
                              void* d_out, int out_size, void* d_ws, size_t ws_size,
                              hipStream_t stream) {
  // Reference dtypes: all float tensors are float32; indices int32. Output f32.
  const float* x    = (const float*)d_in[0];
  const float* hea  = (const float*)d_in[1];
  const int*  nidx  = (const int*)d_in[2];
  const int*  eidx  = (const int*)d_in[3];
  // d_in[4], d_in[5] = node_types / hyperedge_types: unused by reference
  const float* W_lin = (const float*)d_in[6];
  const float* b_lin = (const float*)d_in[7];
  const float* ln_g  = (const float*)d_in[8];
  const float* ln_b  = (const float*)d_in[9];
  const float* W_sh  = (const float*)d_in[10];
  const float* b_sh  = (const float*)d_in[11];
  const float* W_c0  = (const float*)d_in[12];
  const float* b_c0  = (const float*)d_in[13];
  const float* W_c1  = (const float*)d_in[14];
  const float* b_c1  = (const float*)d_in[15];
  float* out = (float*)d_out;

  // workspace layout (f32), 256B aligned. Total ~191 MB.
  char* ws = (char*)d_ws;
  size_t off = 0;
  auto alloc = [&](size_t bytes) {
    size_t o = off;
    off = (off + bytes + 255) & ~(size_t)255;
    return o;
  };
  size_t o_xl0   = alloc((size_t)NROWS * HDIM * 4);               // 76.8 MB (xl0 -> h1 in place)
  size_t o_xl1   = alloc((size_t)NROWS * HDIM * 4);               // 76.8 MB
  size_t o_xa    = alloc((size_t)(N_NODES + N_EDGES) * HDIM * 4); // 15.36 MB
  size_t o_msum  = alloc((size_t)EROWS * HDIM * 4);               // 15.36 MB
  size_t o_alpha = alloc((size_t)NNZV * DSTALK * 4);              // 6 MB
  size_t o_cntN  = alloc((size_t)N_NODES * 4);
  size_t o_cntE  = alloc((size_t)N_EDGES * 4);
  size_t o_Dinv  = alloc((size_t)N_NODES * 4);
  size_t o_Binv  = alloc((size_t)N_EDGES * 4);
  size_t o_Weff  = alloc((size_t)IN_CH * HD * 4);                 // 196 KB
  size_t o_Wm    = alloc((size_t)IN_CH * HDIM * 4);               // 32 KB
  size_t o_cm    = alloc((size_t)HDIM * 4);
  size_t o_c0    = alloc((size_t)HD * 4);

  float* xl0   = (float*)(ws + o_xl0);
  float* xl1   = (float*)(ws + o_xl1);
  float* xa    = (float*)(ws + o_xa);          // node rows [0,N)
  float* eam   = xa + (size_t)N_NODES * HDIM;  // edge rows
  float* msum  = (float*)(ws + o_msum);
  float* alpha = (float*)(ws + o_alpha);
  int*   cntN  = (int*)(ws + o_cntN);
  int*   cntE  = (int*)(ws + o_cntE);
  float* Dinv  = (float*)(ws + o_Dinv);
  float* Binv  = (float*)(ws + o_Binv);
  float* W0eff = (float*)(ws + o_Weff);
  float* Wm    = (float*)(ws + o_Wm);
  float* cm    = (float*)(ws + o_cm);
  float* c0    = (float*)(ws + o_c0);

  const int TOT = NROWS * HDIM;  // 19.2M

  // 0. weight prep
  k_weff<<<(IN_CH * HD + 255) / 256, 256, 0, stream>>>(W_lin, W_c0, W0eff);
  k_wsmall<<<(IN_CH * HDIM + HD + HDIM + 255) / 256, 256, 0, stream>>>(
      W_lin, b_lin, W_c0, Wm, cm, c0);

  // 1. stalk-mean features (fused: xa = [x;hea] @ Wm + cm)
  k_xa<<<(N_NODES + N_EDGES + 63) / 64, 256, 0, stream>>>(x, hea, Wm, cm, xa);

  // 2. degree counts + inverses
  hipMemsetAsync(ws + o_cntN, 0, (size_t)N_NODES * 4, stream);
  hipMemsetAsync(ws + o_cntE, 0, (size_t)N_EDGES * 4, stream);
  k_count<<<(NNZV + 255) / 256, 256, 0, stream>>>(nidx, eidx, cntN, cntE);
  k_inv<<<(N_NODES + 255) / 256, 256, 0, stream>>>(cntN, Dinv, N_NODES);
  k_inv<<<(N_EDGES + 255) / 256, 256, 0, stream>>>(cntE, Binv, N_EDGES);

  // 3. sheaf coefficients alpha [NNZ x 6]
  k_sheaf<<<(NNZV + 3) / 4, 256, 0, stream>>>(xa, eam, nidx, eidx,
                                              ln_g, ln_b, W_sh, b_sh, alpha);

  // 4. conv0: xl0 = xs@W0 (fused via W0eff); then diffusion, bias, ELU (in place)
  k_xl0<<<N_NODES / 16, 384, 0, stream>>>(x, W0eff, c0, xl0);
  hipMemsetAsync(ws + o_msum, 0, (size_t)EROWS * HDIM * 4, stream);
  k_scatter_e<<<(NNZV + 3) / 4, 256, 0, stream>>>(nidx, eidx, alpha, xl0, msum);
  k_bias<<<(TOT + 255) / 256, 256, 0, stream>>>(xl0, b_c0, xl0, TOT);
  k_scatter_n<<<(NNZV + 3) / 4, 256, 0, stream>>>(nidx, eidx, alpha, msum, Dinv, Binv, xl0);
  k_elu<<<(TOT + 255) / 256, 256, 0, stream>>>(xl0, TOT);  // xl0 now holds h1

  // 5. conv1: xl1 = h1 @ W1; diffusion; acc directly in d_out; final ELU
  k_xw<<<NROWS / 16, 256, 0, stream>>>(xl0, W_c1, xl1);
  hipMemsetAsync(ws + o_msum, 0, (size_t)EROWS * HDIM * 4, stream);
  k_scatter_e<<<(NNZV + 3) / 4, 256, 0, stream>>>(nidx, eidx, alpha, xl1, msum);
  k_bias<<<(TOT + 255) / 256, 256, 0, stream>>>(xl1, b_c1, out, TOT);
  k_scatter_n<<<(NNZV + 3) / 4, 256, 0, stream>>>(nidx, eidx, alpha, msum, Dinv, Binv, out);
  k_elu<<<(TOT + 255) / 256, 256, 0, stream>>>(out, TOT);

  (void)in_sizes; (void)n_in; (void)out_size; (void)ws_size;
}

// Round 3
// 1045.836 us; speedup vs baseline: 1.7846x; 1.7846x over previous
//
#include <hip/hip_runtime.h>
#include <hip/hip_bf16.h>

// Problem constants (from reference)
#define N_NODES 50000
#define N_EDGES 10000
#define NNZV    250000
#define IN_CH   128
#define HDIM    64
#define DSTALK  6
#define HD      384   // HDIM * DSTALK
#define NROWS   (N_NODES * DSTALK)   // 300000
#define EROWS   (N_EDGES * DSTALK)   // 60000

// ---------------------------------------------------------------------------
// W-prep 1: W0eff[k][j=r*64+h] = sum_m W_lin[k][r*64+m] * W0[m][h]
// (fuses input projection with conv0's weight: xs@W0 == x@W0eff + c0)
__global__ __launch_bounds__(256) void k_weff(
    const float* __restrict__ W_lin, const float* __restrict__ W0,
    float* __restrict__ W0eff) {
  int idx = blockIdx.x * blockDim.x + threadIdx.x;
  if (idx >= IN_CH * HD) return;
  int k = idx / HD, j = idx - k * HD;
  int r = j >> 6, h = j & 63;
  float s = 0.f;
#pragma unroll 8
  for (int m = 0; m < HDIM; m++)
    s += W_lin[k * HD + r * HDIM + m] * W0[m * HDIM + h];
  W0eff[idx] = s;
}

// W-prep 2: Wm (stalk-mean of W_lin), cm (stalk-mean of b_lin),
//           c0[j] = sum_m b_lin[r*64+m] * W0[m][h]
__global__ __launch_bounds__(256) void k_wsmall(
    const float* __restrict__ W_lin, const float* __restrict__ b_lin,
    const float* __restrict__ W0,
    float* __restrict__ Wm, float* __restrict__ cm, float* __restrict__ c0) {
  int idx = blockIdx.x * blockDim.x + threadIdx.x;
  if (idx < IN_CH * HDIM) {            // Wm
    int k = idx >> 6, h = idx & 63;
    float s = 0.f;
#pragma unroll
    for (int r = 0; r < DSTALK; r++) s += W_lin[k * HD + r * HDIM + h];
    Wm[idx] = s * (1.f / 6.f);
  } else if (idx < IN_CH * HDIM + HD) {  // c0
    int j = idx - IN_CH * HDIM;
    int r = j >> 6, h = j & 63;
    float s = 0.f;
#pragma unroll 8
    for (int m = 0; m < HDIM; m++) s += b_lin[r * HDIM + m] * W0[m * HDIM + h];
    c0[j] = s;
  } else if (idx < IN_CH * HDIM + HD + HDIM) {  // cm
    int h = idx - IN_CH * HDIM - HD;
    float s = 0.f;
#pragma unroll
    for (int r = 0; r < DSTALK; r++) s += b_lin[r * HDIM + h];
    cm[h] = s * (1.f / 6.f);
  }
}

// ---------------------------------------------------------------------------
// xa[row][h] = sum_k in[row][k] * Wm[k][h] + cm[h]; rows 0..N-1 nodes, then edges
__global__ __launch_bounds__(256) void k_xa(
    const float* __restrict__ x, const float* __restrict__ ea,
    const float* __restrict__ Wm, const float* __restrict__ cm,
    float* __restrict__ xa) {
  __shared__ float lx[64][IN_CH];
  const int row0 = blockIdx.x * 64;
  const int tid = threadIdx.x;
  for (int i = tid; i < 64 * IN_CH; i += 256) {
    int r = i >> 7, k = i & 127;
    int row = row0 + r;
    float v = 0.f;
    if (row < N_NODES) v = x[row * IN_CH + k];
    else if (row < N_NODES + N_EDGES) v = ea[(row - N_NODES) * IN_CH + k];
    lx[r][k] = v;
  }
  __syncthreads();
  const int col = tid & 63, rg = tid >> 6;  // 4 groups x 16 rows
  float acc[16];
#pragma unroll
  for (int i = 0; i < 16; i++) acc[i] = 0.f;
  for (int k = 0; k < IN_CH; k++) {
    float w = Wm[k * HDIM + col];
#pragma unroll
    for (int i = 0; i < 16; i++) acc[i] += lx[rg * 16 + i][k] * w;
  }
  float c = cm[col];
#pragma unroll
  for (int i = 0; i < 16; i++) {
    int row = row0 + rg * 16 + i;
    if (row < N_NODES + N_EDGES) xa[row * HDIM + col] = acc[i] + c;
  }
}

// ---------------------------------------------------------------------------
// xl0[n*384 + j] = sum_k x[n][k] * W0eff[k][j] + c0[j]   (this IS xs@W0)
__global__ __launch_bounds__(384) void k_xl0(
    const float* __restrict__ x, const float* __restrict__ W0eff,
    const float* __restrict__ c0, float* __restrict__ xl0) {
  __shared__ float lx[16][IN_CH];
  const int row0 = blockIdx.x * 16;
  const int tid = threadIdx.x;
  for (int i = tid; i < 16 * IN_CH; i += 384) {
    int r = i >> 7, k = i & 127;
    int row = row0 + r;
    lx[r][k] = (row < N_NODES) ? x[row * IN_CH + k] : 0.f;
  }
  __syncthreads();
  const int j = tid;  // 0..383
  float acc[16];
#pragma unroll
  for (int r = 0; r < 16; r++) acc[r] = 0.f;
  for (int k = 0; k < IN_CH; k++) {
    float w = W0eff[k * HD + j];
#pragma unroll
    for (int r = 0; r < 16; r++) acc[r] += lx[r][k] * w;
  }
  const float bb = c0[j];
#pragma unroll
  for (int r = 0; r < 16; r++) {
    int row = row0 + r;
    if (row < N_NODES) xl0[(size_t)row * HD + j] = acc[r] + bb;
  }
}

// ---------------------------------------------------------------------------
// per-incidence LayerNorm(128) + W_sheaf + sigmoid -> alpha [NNZ x 6]
__global__ __launch_bounds__(256) void k_sheaf(
    const float* __restrict__ xa, const float* __restrict__ eam,
    const int* __restrict__ nidx, const int* __restrict__ eidx,
    const float* __restrict__ g, const float* __restrict__ bln,
    const float* __restrict__ Ws, const float* __restrict__ bs,
    float* __restrict__ alpha) {
  int w = (blockIdx.x * blockDim.x + threadIdx.x) >> 6;
  int lane = threadIdx.x & 63;
  if (w >= NNZV) return;
  int n = nidx[w], e = eidx[w];
  float f1 = xa[n * HDIM + lane];
  float f2 = eam[e * HDIM + lane];
  float s = f1 + f2;
#pragma unroll
  for (int o = 32; o; o >>= 1) s += __shfl_xor(s, o);
  float mu = s * (1.f / 128.f);
  float d1 = f1 - mu, d2 = f2 - mu;
  float v = d1 * d1 + d2 * d2;
#pragma unroll
  for (int o = 32; o; o >>= 1) v += __shfl_xor(v, o);
  float rs = rsqrtf(v * (1.f / 128.f) + 1e-5f);
  float n1 = d1 * rs * g[lane] + bln[lane];
  float n2 = d2 * rs * g[64 + lane] + bln[64 + lane];
#pragma unroll
  for (int r = 0; r < DSTALK; r++) {
    float t = n1 * Ws[lane * DSTALK + r] + n2 * Ws[(64 + lane) * DSTALK + r];
#pragma unroll
    for (int o = 32; o; o >>= 1) t += __shfl_xor(t, o);
    if (lane == 0) {
      float z = t + bs[r];
      alpha[w * DSTALK + r] = 1.f / (1.f + expf(-z));
    }
  }
}

// ---------------------------------------------------------------------------
// degree counts
__global__ void k_count(const int* __restrict__ nidx, const int* __restrict__ eidx,
                        int* __restrict__ cntN, int* __restrict__ cntE) {
  int j = blockIdx.x * blockDim.x + threadIdx.x;
  if (j < NNZV) {
    atomicAdd(&cntN[nidx[j]], 1);
    atomicAdd(&cntE[eidx[j]], 1);
  }
}

// single-block exclusive scan: cnt[0..n) -> row[0..n], fill copy, inverse counts
__global__ __launch_bounds__(256) void k_scan(
    const int* __restrict__ cnt, int n,
    int* __restrict__ row, int* __restrict__ fill, float* __restrict__ inv) {
  __shared__ int part[256];
  __shared__ int base[257];
  int t = threadIdx.x;
  int chunk = (n + 255) / 256;
  int lo = t * chunk, hi = lo + chunk;
  if (hi > n) hi = n;
  int s = 0;
  for (int i = lo; i < hi; i++) s += cnt[i];
  part[t] = s;
  __syncthreads();
  if (t == 0) {
    int acc = 0;
    for (int i = 0; i < 256; i++) { base[i] = acc; acc += part[i]; }
    base[256] = acc;
  }
  __syncthreads();
  int b = base[t];
  for (int i = lo; i < hi; i++) {
    int c = cnt[i];
    row[i] = b;
    fill[i] = b;
    inv[i] = c > 0 ? 1.f / (float)c : 0.f;
    b += c;
  }
  if (t == 0) row[n] = base[256];
}

// fill CSR incidence lists (order within a segment is arbitrary)
__global__ void k_fill(const int* __restrict__ nidx, const int* __restrict__ eidx,
                       int* __restrict__ fillN, int* __restrict__ fillE,
                       int* __restrict__ jlN, int* __restrict__ jlE) {
  int j = blockIdx.x * blockDim.x + threadIdx.x;
  if (j < NNZV) {
    int p = atomicAdd(&fillN[nidx[j]], 1);
    jlN[p] = j;
    int q = atomicAdd(&fillE[eidx[j]], 1);
    jlE[q] = j;
  }
}

// ---------------------------------------------------------------------------
// conv1 GEMM: xl = xin @ W (rows=300000). Row-local => safe in-place (xl==xin).
__global__ __launch_bounds__(256) void k_xw(const float* __restrict__ xin,
                                            const float* __restrict__ W,
                                            float* __restrict__ xl) {
  __shared__ float lw[64][64];
  __shared__ float lx[16][64];
  const int tid = threadIdx.x;
  for (int i = tid; i < 64 * 64; i += 256) lw[i >> 6][i & 63] = W[i];
  const int row0 = blockIdx.x * 16;
  for (int i = tid; i < 16 * 64; i += 256)
    lx[i >> 6][i & 63] = xin[(size_t)(row0 + (i >> 6)) * HDIM + (i & 63)];
  __syncthreads();
  const int c = tid & 63, rg = tid >> 6;
  float acc[4];
#pragma unroll
  for (int rr = 0; rr < 4; rr++) acc[rr] = 0.f;
  for (int k = 0; k < 64; k++) {
    float w = lw[k][c];
#pragma unroll
    for (int rr = 0; rr < 4; rr++) acc[rr] += lx[rg * 4 + rr][k] * w;
  }
  __syncthreads();  // in-place safety: all reads done before writes race ahead
#pragma unroll
  for (int rr = 0; rr < 4; rr++)
    xl[(size_t)(row0 + rg * 4 + rr) * HDIM + c] = acc[rr];
}

// ---------------------------------------------------------------------------
// gather to edges: one wave per edge; msum[e,r,:] = Binv[e]*sum_j alpha[j,r]*xl[n_j,r,:]
__global__ __launch_bounds__(256) void k_gather_e(
    const int* __restrict__ rowE, const int* __restrict__ jlE,
    const int* __restrict__ nidx, const float* __restrict__ alpha,
    const float* __restrict__ xl, const float* __restrict__ Binv,
    float* __restrict__ msum) {
  int e = (blockIdx.x * blockDim.x + threadIdx.x) >> 6;
  int lane = threadIdx.x & 63;
  if (e >= N_EDGES) return;
  float acc[DSTALK];
#pragma unroll
  for (int r = 0; r < DSTALK; r++) acc[r] = 0.f;
  const int lo = rowE[e], hi = rowE[e + 1];
  for (int p = lo; p < hi; p++) {
    const int j = jlE[p];
    const int n = nidx[j];
    const float* __restrict__ xr = xl + (size_t)n * HD + lane;
    const float* __restrict__ ar = alpha + (size_t)j * DSTALK;
#pragma unroll
    for (int r = 0; r < DSTALK; r++) acc[r] += ar[r] * xr[r * HDIM];
  }
  const float bv = Binv[e];
  float* __restrict__ mr = msum + (size_t)e * HD + lane;
#pragma unroll
  for (int r = 0; r < DSTALK; r++) mr[r * HDIM] = acc[r] * bv;
}

// gather back to nodes + bias + ELU epilogue: one wave per node
// out[n,r,:] = elu( xl[n,r,:] + bias - Dinv[n]*sum_j alpha[j,r]*msum[e_j,r,:] )
__global__ __launch_bounds__(256) void k_gather_n(
    const int* __restrict__ rowN, const int* __restrict__ jlN,
    const int* __restrict__ eidx, const float* __restrict__ alpha,
    const float* __restrict__ msum, const float* __restrict__ Dinv,
    const float* __restrict__ xl, const float* __restrict__ bias,
    float* __restrict__ outp) {
  int n = (blockIdx.x * blockDim.x + threadIdx.x) >> 6;
  int lane = threadIdx.x & 63;
  if (n >= N_NODES) return;
  float acc[DSTALK];
#pragma unroll
  for (int r = 0; r < DSTALK; r++) acc[r] = 0.f;
  const int lo = rowN[n], hi = rowN[n + 1];
  for (int p = lo; p < hi; p++) {
    const int j = jlN[p];
    const int e = eidx[j];
    const float* __restrict__ mr = msum + (size_t)e * HD + lane;
    const float* __restrict__ ar = alpha + (size_t)j * DSTALK;
#pragma unroll
    for (int r = 0; r < DSTALK; r++) acc[r] += ar[r] * mr[r * HDIM];
  }
  const float dv = Dinv[n];
  const float bb = bias[lane];
  const float* __restrict__ xr = xl + (size_t)n * HD + lane;
  float* __restrict__ orow = outp + (size_t)n * HD + lane;
#pragma unroll
  for (int r = 0; r < DSTALK; r++) {
    float v = xr[r * HDIM] + bb - dv * acc[r];
    orow[r * HDIM] = v > 0.f ? v : expm1f(v);
  }
}

// ---------------------------------------------------------------------------
extern "C" void kernel_launch(void* const* d_in, const int* in_sizes, int n_in,
                              void* d_out, int out_size, void* d_ws, size_t ws_size,
                              hipStream_t stream) {
  const float* x    = (const float*)d_in[0];
  const float* hea  = (const float*)d_in[1];
  const int*  nidx  = (const int*)d_in[2];
  const int*  eidx  = (const int*)d_in[3];
  // d_in[4], d_in[5] = node_types / hyperedge_types: unused by reference
  const float* W_lin = (const float*)d_in[6];
  const float* b_lin = (const float*)d_in[7];
  const float* ln_g  = (const float*)d_in[8];
  const float* ln_b  = (const float*)d_in[9];
  const float* W_sh  = (const float*)d_in[10];
  const float* b_sh  = (const float*)d_in[11];
  const float* W_c0  = (const float*)d_in[12];
  const float* b_c0  = (const float*)d_in[13];
  const float* W_c1  = (const float*)d_in[14];
  const float* b_c1  = (const float*)d_in[15];
  float* out = (float*)d_out;

  // workspace layout (f32), 256B aligned. Total ~117 MB.
  char* ws = (char*)d_ws;
  size_t off = 0;
  auto alloc = [&](size_t bytes) {
    size_t o = off;
    off = (off + bytes + 255) & ~(size_t)255;
    return o;
  };
  size_t o_xl0   = alloc((size_t)NROWS * HDIM * 4);               // 76.8 MB (xl0 -> h1 -> xl1 in place)
  size_t o_xa    = alloc((size_t)(N_NODES + N_EDGES) * HDIM * 4); // 15.36 MB
  size_t o_msum  = alloc((size_t)EROWS * HDIM * 4);               // 15.36 MB
  size_t o_alpha = alloc((size_t)NNZV * DSTALK * 4);              // 6 MB
  size_t o_jlN   = alloc((size_t)NNZV * 4);                       // 1 MB
  size_t o_jlE   = alloc((size_t)NNZV * 4);                       // 1 MB
  size_t o_cntN  = alloc((size_t)N_NODES * 4);
  size_t o_cntE  = alloc((size_t)N_EDGES * 4);
  size_t o_rowN  = alloc((size_t)(N_NODES + 1) * 4);
  size_t o_rowE  = alloc((size_t)(N_EDGES + 1) * 4);
  size_t o_filN  = alloc((size_t)N_NODES * 4);
  size_t o_filE  = alloc((size_t)N_EDGES * 4);
  size_t o_Dinv  = alloc((size_t)N_NODES * 4);
  size_t o_Binv  = alloc((size_t)N_EDGES * 4);
  size_t o_Weff  = alloc((size_t)IN_CH * HD * 4);                 // 196 KB
  size_t o_Wm    = alloc((size_t)IN_CH * HDIM * 4);               // 32 KB
  size_t o_cm    = alloc((size_t)HDIM * 4);
  size_t o_c0    = alloc((size_t)HD * 4);

  float* xl0   = (float*)(ws + o_xl0);
  float* xa    = (float*)(ws + o_xa);          // node rows [0,N)
  float* eam   = xa + (size_t)N_NODES * HDIM;  // edge rows
  float* msum  = (float*)(ws + o_msum);
  float* alpha = (float*)(ws + o_alpha);
  int*   jlN   = (int*)(ws + o_jlN);
  int*   jlE   = (int*)(ws + o_jlE);
  int*   cntN  = (int*)(ws + o_cntN);
  int*   cntE  = (int*)(ws + o_cntE);
  int*   rowN  = (int*)(ws + o_rowN);
  int*   rowE  = (int*)(ws + o_rowE);
  int*   filN  = (int*)(ws + o_filN);
  int*   filE  = (int*)(ws + o_filE);
  float* Dinv  = (float*)(ws + o_Dinv);
  float* Binv  = (float*)(ws + o_Binv);
  float* W0eff = (float*)(ws + o_Weff);
  float* Wm    = (float*)(ws + o_Wm);
  float* cm    = (float*)(ws + o_cm);
  float* c0    = (float*)(ws + o_c0);

  // 0. weight prep
  k_weff<<<(IN_CH * HD + 255) / 256, 256, 0, stream>>>(W_lin, W_c0, W0eff);
  k_wsmall<<<(IN_CH * HDIM + HD + HDIM + 255) / 256, 256, 0, stream>>>(
      W_lin, b_lin, W_c0, Wm, cm, c0);

  // 1. CSR build: counts -> scans (+Dinv/Binv) -> fill
  hipMemsetAsync(ws + o_cntN, 0, (size_t)N_NODES * 4, stream);
  hipMemsetAsync(ws + o_cntE, 0, (size_t)N_EDGES * 4, stream);
  k_count<<<(NNZV + 255) / 256, 256, 0, stream>>>(nidx, eidx, cntN, cntE);
  k_scan<<<1, 256, 0, stream>>>(cntN, N_NODES, rowN, filN, Dinv);
  k_scan<<<1, 256, 0, stream>>>(cntE, N_EDGES, rowE, filE, Binv);
  k_fill<<<(NNZV + 255) / 256, 256, 0, stream>>>(nidx, eidx, filN, filE, jlN, jlE);

  // 2. stalk-mean features (fused: xa = [x;hea] @ Wm + cm)
  k_xa<<<(N_NODES + N_EDGES + 63) / 64, 256, 0, stream>>>(x, hea, Wm, cm, xa);

  // 3. sheaf coefficients alpha [NNZ x 6]
  k_sheaf<<<(NNZV + 3) / 4, 256, 0, stream>>>(xa, eam, nidx, eidx,
                                              ln_g, ln_b, W_sh, b_sh, alpha);

  // 4. conv0: xl0 = xs@W0 (fused via W0eff); gather-diffusion; bias+ELU fused
  k_xl0<<<N_NODES / 16, 384, 0, stream>>>(x, W0eff, c0, xl0);
  k_gather_e<<<(N_EDGES + 3) / 4, 256, 0, stream>>>(rowE, jlE, nidx, alpha, xl0, Binv, msum);
  k_gather_n<<<(N_NODES + 3) / 4, 256, 0, stream>>>(rowN, jlN, eidx, alpha, msum, Dinv,
                                                    xl0, b_c0, xl0);  // xl0 now holds h1

  // 5. conv1: xl1 = h1@W1 (in place); gather-diffusion; bias+ELU into d_out
  k_xw<<<NROWS / 16, 256, 0, stream>>>(xl0, W_c1, xl0);
  k_gather_e<<<(N_EDGES + 3) / 4, 256, 0, stream>>>(rowE, jlE, nidx, alpha, xl0, Binv, msum);
  k_gather_n<<<(N_NODES + 3) / 4, 256, 0, stream>>>(rowN, jlN, eidx, alpha, msum, Dinv,
                                                    xl0, b_c1, out);

  (void)in_sizes; (void)n_in; (void)out_size; (void)ws_size;
}

// Round 4
// 924.187 us; speedup vs baseline: 2.0196x; 1.1316x over previous
//
#include <hip/hip_runtime.h>
#include <hip/hip_bf16.h>

// Problem constants (from reference)
#define N_NODES 50000
#define N_EDGES 10000
#define NNZV    250000
#define IN_CH   128
#define HDIM    64
#define DSTALK  6
#define HD      384   // HDIM * DSTALK
#define NROWS   (N_NODES * DSTALK)   // 300000
#define EROWS   (N_EDGES * DSTALK)   // 60000

// ---------------------------------------------------------------------------
// W-prep 1: W0eff[k][j=r*64+h] = sum_m W_lin[k][r*64+m] * W0[m][h]
__global__ __launch_bounds__(256) void k_weff(
    const float* __restrict__ W_lin, const float* __restrict__ W0,
    float* __restrict__ W0eff) {
  int idx = blockIdx.x * blockDim.x + threadIdx.x;
  if (idx >= IN_CH * HD) return;
  int k = idx / HD, j = idx - k * HD;
  int r = j >> 6, h = j & 63;
  float s = 0.f;
#pragma unroll 8
  for (int m = 0; m < HDIM; m++)
    s += W_lin[k * HD + r * HDIM + m] * W0[m * HDIM + h];
  W0eff[idx] = s;
}

// W-prep 2: Wm, cm, c0  +  sheaf-closed-form tables gwN, gwE, G, K
//   gwN[h*6+r] = g[h]*Ws[h*6+r]          (node half of LN scale * W_sheaf)
//   gwE[h*6+r] = g[64+h]*Ws[(64+h)*6+r]  (edge half)
//   G[r] = sum_{i<128} g[i]*Ws[i*6+r]
//   K[r] = sum_{i<128} bln[i]*Ws[i*6+r] + bs[r]
#define WS_BASE (IN_CH * HDIM + HD + HDIM)   // 8640
__global__ __launch_bounds__(256) void k_wsmall(
    const float* __restrict__ W_lin, const float* __restrict__ b_lin,
    const float* __restrict__ W0,
    const float* __restrict__ g, const float* __restrict__ bln,
    const float* __restrict__ Ws, const float* __restrict__ bs,
    float* __restrict__ Wm, float* __restrict__ cm, float* __restrict__ c0,
    float* __restrict__ gwN, float* __restrict__ gwE,
    float* __restrict__ G, float* __restrict__ K) {
  int idx = blockIdx.x * blockDim.x + threadIdx.x;
  if (idx < IN_CH * HDIM) {            // Wm
    int k = idx >> 6, h = idx & 63;
    float s = 0.f;
#pragma unroll
    for (int r = 0; r < DSTALK; r++) s += W_lin[k * HD + r * HDIM + h];
    Wm[idx] = s * (1.f / 6.f);
  } else if (idx < IN_CH * HDIM + HD) {  // c0
    int j = idx - IN_CH * HDIM;
    int r = j >> 6, h = j & 63;
    float s = 0.f;
#pragma unroll 8
    for (int m = 0; m < HDIM; m++) s += b_lin[r * HDIM + m] * W0[m * HDIM + h];
    c0[j] = s;
  } else if (idx < WS_BASE) {  // cm
    int h = idx - IN_CH * HDIM - HD;
    float s = 0.f;
#pragma unroll
    for (int r = 0; r < DSTALK; r++) s += b_lin[r * HDIM + h];
    cm[h] = s * (1.f / 6.f);
  } else if (idx < WS_BASE + 384) {      // gwN
    int i = idx - WS_BASE;
    int h = i / 6, r = i - h * 6;
    gwN[i] = g[h] * Ws[h * DSTALK + r];
  } else if (idx < WS_BASE + 768) {      // gwE
    int i = idx - WS_BASE - 384;
    int h = i / 6, r = i - h * 6;
    gwE[i] = g[64 + h] * Ws[(64 + h) * DSTALK + r];
  } else if (idx < WS_BASE + 774) {      // G
    int r = idx - WS_BASE - 768;
    float s = 0.f;
    for (int i = 0; i < 2 * HDIM; i++) s += g[i] * Ws[i * DSTALK + r];
    G[r] = s;
  } else if (idx < WS_BASE + 780) {      // K
    int r = idx - WS_BASE - 774;
    float s = 0.f;
    for (int i = 0; i < 2 * HDIM; i++) s += bln[i] * Ws[i * DSTALK + r];
    K[r] = s + bs[r];
  }
}

// ---------------------------------------------------------------------------
// Fused: row features xa = [x;hea]@Wm + cm (kept in LDS only) -> per-row
// sufficient stats [s1, s2, p0..p5] for the closed-form sheaf LN.
__global__ __launch_bounds__(256) void k_xa_stats(
    const float* __restrict__ x, const float* __restrict__ ea,
    const float* __restrict__ Wm, const float* __restrict__ cm,
    const float* __restrict__ gwN, const float* __restrict__ gwE,
    float* __restrict__ stats) {
  __shared__ float lx[64][IN_CH];      // 32 KB input tile
  __shared__ float ox[64][HDIM + 1];   // 16.6 KB feature tile (padded)
  __shared__ float lgw[2][64 * DSTALK];
  const int row0 = blockIdx.x * 64;
  const int tid = threadIdx.x;
  for (int i = tid; i < 2 * 64 * DSTALK; i += 256) {
    int which = i / 384, k = i - which * 384;
    lgw[which][k] = which ? gwE[k] : gwN[k];
  }
  for (int i = tid; i < 64 * IN_CH; i += 256) {
    int r = i >> 7, k = i & 127;
    int row = row0 + r;
    float v = 0.f;
    if (row < N_NODES) v = x[row * IN_CH + k];
    else if (row < N_NODES + N_EDGES) v = ea[(row - N_NODES) * IN_CH + k];
    lx[r][k] = v;
  }
  __syncthreads();
  const int col = tid & 63, rg = tid >> 6;  // 4 groups x 16 rows
  float acc[16];
#pragma unroll
  for (int i = 0; i < 16; i++) acc[i] = 0.f;
  for (int k = 0; k < IN_CH; k++) {
    float w = Wm[k * HDIM + col];
#pragma unroll
    for (int i = 0; i < 16; i++) acc[i] += lx[rg * 16 + i][k] * w;
  }
  const float c = cm[col];
#pragma unroll
  for (int i = 0; i < 16; i++) ox[rg * 16 + i][col] = acc[i] + c;
  __syncthreads();
  // 512 reduction tasks: (row, stat). stat: 0=s1, 1=s2, 2..7=p[r]
  for (int t = tid; t < 512; t += 256) {
    int row = t >> 3, st = t & 7;
    int grow = row0 + row;
    if (grow >= N_NODES + N_EDGES) continue;
    const float* __restrict__ gw = (grow >= N_NODES) ? lgw[1] : lgw[0];
    float s = 0.f;
    if (st == 0) {
#pragma unroll 8
      for (int h = 0; h < HDIM; h++) s += ox[row][h];
    } else if (st == 1) {
#pragma unroll 8
      for (int h = 0; h < HDIM; h++) { float v = ox[row][h]; s += v * v; }
    } else {
      int r = st - 2;
#pragma unroll 8
      for (int h = 0; h < HDIM; h++) s += ox[row][h] * gw[h * DSTALK + r];
    }
    stats[(size_t)grow * 8 + st] = s;
  }
}

// ---------------------------------------------------------------------------
// xl0[n*384 + j] = sum_k x[n][k] * W0eff[k][j] + c0[j]   (this IS xs@W0)
__global__ __launch_bounds__(384) void k_xl0(
    const float* __restrict__ x, const float* __restrict__ W0eff,
    const float* __restrict__ c0, float* __restrict__ xl0) {
  __shared__ float lx[16][IN_CH];
  const int row0 = blockIdx.x * 16;
  const int tid = threadIdx.x;
  for (int i = tid; i < 16 * IN_CH; i += 384) {
    int r = i >> 7, k = i & 127;
    int row = row0 + r;
    lx[r][k] = (row < N_NODES) ? x[row * IN_CH + k] : 0.f;
  }
  __syncthreads();
  const int j = tid;  // 0..383
  float acc[16];
#pragma unroll
  for (int r = 0; r < 16; r++) acc[r] = 0.f;
  for (int k = 0; k < IN_CH; k++) {
    float w = W0eff[k * HD + j];
#pragma unroll
    for (int r = 0; r < 16; r++) acc[r] += lx[r][k] * w;
  }
  const float bb = c0[j];
#pragma unroll
  for (int r = 0; r < 16; r++) {
    int row = row0 + r;
    if (row < N_NODES) xl0[(size_t)row * HD + j] = acc[r] + bb;
  }
}

// ---------------------------------------------------------------------------
// closed-form sheaf coefficients: one THREAD per incidence
__global__ __launch_bounds__(256) void k_sheaf2(
    const int* __restrict__ nidx, const int* __restrict__ eidx,
    const float* __restrict__ stats,
    const float* __restrict__ G, const float* __restrict__ K,
    float* __restrict__ alpha) {
  int j = blockIdx.x * blockDim.x + threadIdx.x;
  if (j >= NNZV) return;
  int n = nidx[j], e = eidx[j];
  const float4* __restrict__ sn = (const float4*)(stats + (size_t)n * 8);
  const float4* __restrict__ se = (const float4*)(stats + ((size_t)(N_NODES + e)) * 8);
  float4 a0 = sn[0], a1 = sn[1];
  float4 b0 = se[0], b1 = se[1];
  float mu = (a0.x + b0.x) * (1.f / 128.f);
  float var = (a0.y + b0.y) * (1.f / 128.f) - mu * mu;
  float rs = rsqrtf(var + 1e-5f);
  float p[DSTALK] = {a0.z + b0.z, a0.w + b0.w, a1.x + b1.x,
                     a1.y + b1.y, a1.z + b1.z, a1.w + b1.w};
#pragma unroll
  for (int r = 0; r < DSTALK; r++) {
    float z = rs * (p[r] - mu * G[r]) + K[r];
    alpha[(size_t)j * DSTALK + r] = 1.f / (1.f + expf(-z));
  }
}

// ---------------------------------------------------------------------------
// degree counts
__global__ void k_count(const int* __restrict__ nidx, const int* __restrict__ eidx,
                        int* __restrict__ cntN, int* __restrict__ cntE) {
  int j = blockIdx.x * blockDim.x + threadIdx.x;
  if (j < NNZV) {
    atomicAdd(&cntN[nidx[j]], 1);
    atomicAdd(&cntE[eidx[j]], 1);
  }
}

// single-block exclusive scan: cnt -> row offsets, fill copy, inverse counts
__global__ __launch_bounds__(256) void k_scan(
    const int* __restrict__ cnt, int n,
    int* __restrict__ row, int* __restrict__ fill, float* __restrict__ inv) {
  __shared__ int part[256];
  __shared__ int base[257];
  int t = threadIdx.x;
  int chunk = (n + 255) / 256;
  int lo = t * chunk, hi = lo + chunk;
  if (hi > n) hi = n;
  int s = 0;
  for (int i = lo; i < hi; i++) s += cnt[i];
  part[t] = s;
  __syncthreads();
  if (t == 0) {
    int acc = 0;
    for (int i = 0; i < 256; i++) { base[i] = acc; acc += part[i]; }
    base[256] = acc;
  }
  __syncthreads();
  int b = base[t];
  for (int i = lo; i < hi; i++) {
    int c = cnt[i];
    row[i] = b;
    fill[i] = b;
    inv[i] = c > 0 ? 1.f / (float)c : 0.f;
    b += c;
  }
  if (t == 0) row[n] = base[256];
}

// fill CSR incidence lists (order within a segment is arbitrary)
__global__ void k_fill(const int* __restrict__ nidx, const int* __restrict__ eidx,
                       int* __restrict__ fillN, int* __restrict__ fillE,
                       int* __restrict__ jlN, int* __restrict__ jlE) {
  int j = blockIdx.x * blockDim.x + threadIdx.x;
  if (j < NNZV) {
    int p = atomicAdd(&fillN[nidx[j]], 1);
    jlN[p] = j;
    int q = atomicAdd(&fillE[eidx[j]], 1);
    jlE[q] = j;
  }
}

// ---------------------------------------------------------------------------
// conv1 GEMM: xl = xin @ W (rows=300000). Row-local => safe in-place.
__global__ __launch_bounds__(256) void k_xw(const float* __restrict__ xin,
                                            const float* __restrict__ W,
                                            float* __restrict__ xl) {
  __shared__ float lw[64][64];
  __shared__ float lx[16][64];
  const int tid = threadIdx.x;
  for (int i = tid; i < 64 * 64; i += 256) lw[i >> 6][i & 63] = W[i];
  const int row0 = blockIdx.x * 16;
  for (int i = tid; i < 16 * 64; i += 256)
    lx[i >> 6][i & 63] = xin[(size_t)(row0 + (i >> 6)) * HDIM + (i & 63)];
  __syncthreads();
  const int c = tid & 63, rg = tid >> 6;
  float acc[4];
#pragma unroll
  for (int rr = 0; rr < 4; rr++) acc[rr] = 0.f;
  for (int k = 0; k < 64; k++) {
    float w = lw[k][c];
#pragma unroll
    for (int rr = 0; rr < 4; rr++) acc[rr] += lx[rg * 4 + rr][k] * w;
  }
  __syncthreads();  // in-place safety
#pragma unroll
  for (int rr = 0; rr < 4; rr++)
    xl[(size_t)(row0 + rg * 4 + rr) * HDIM + c] = acc[rr];
}

// ---------------------------------------------------------------------------
// gather to edges: one wave per edge; msum[e,r,:] = Binv[e]*sum_j alpha[j,r]*xl[n_j,r,:]
__global__ __launch_bounds__(256) void k_gather_e(
    const int* __restrict__ rowE, const int* __restrict__ jlE,
    const int* __restrict__ nidx, const float* __restrict__ alpha,
    const float* __restrict__ xl, const float* __restrict__ Binv,
    float* __restrict__ msum) {
  int e = (blockIdx.x * blockDim.x + threadIdx.x) >> 6;
  int lane = threadIdx.x & 63;
  if (e >= N_EDGES) return;
  float acc[DSTALK];
#pragma unroll
  for (int r = 0; r < DSTALK; r++) acc[r] = 0.f;
  const int lo = rowE[e], hi = rowE[e + 1];
  for (int p = lo; p < hi; p++) {
    const int j = jlE[p];
    const int n = nidx[j];
    const float* __restrict__ xr = xl + (size_t)n * HD + lane;
    const float* __restrict__ ar = alpha + (size_t)j * DSTALK;
#pragma unroll
    for (int r = 0; r < DSTALK; r++) acc[r] += ar[r] * xr[r * HDIM];
  }
  const float bv = Binv[e];
  float* __restrict__ mr = msum + (size_t)e * HD + lane;
#pragma unroll
  for (int r = 0; r < DSTALK; r++) mr[r * HDIM] = acc[r] * bv;
}

// gather back to nodes + bias + ELU epilogue: one wave per node
__global__ __launch_bounds__(256) void k_gather_n(
    const int* __restrict__ rowN, const int* __restrict__ jlN,
    const int* __restrict__ eidx, const float* __restrict__ alpha,
    const float* __restrict__ msum, const float* __restrict__ Dinv,
    const float* __restrict__ xl, const float* __restrict__ bias,
    float* __restrict__ outp) {
  int n = (blockIdx.x * blockDim.x + threadIdx.x) >> 6;
  int lane = threadIdx.x & 63;
  if (n >= N_NODES) return;
  float acc[DSTALK];
#pragma unroll
  for (int r = 0; r < DSTALK; r++) acc[r] = 0.f;
  const int lo = rowN[n], hi = rowN[n + 1];
  for (int p = lo; p < hi; p++) {
    const int j = jlN[p];
    const int e = eidx[j];
    const float* __restrict__ mr = msum + (size_t)e * HD + lane;
    const float* __restrict__ ar = alpha + (size_t)j * DSTALK;
#pragma unroll
    for (int r = 0; r < DSTALK; r++) acc[r] += ar[r] * mr[r * HDIM];
  }
  const float dv = Dinv[n];
  const float bb = bias[lane];
  const float* __restrict__ xr = xl + (size_t)n * HD + lane;
  float* __restrict__ orow = outp + (size_t)n * HD + lane;
#pragma unroll
  for (int r = 0; r < DSTALK; r++) {
    float v = xr[r * HDIM] + bb - dv * acc[r];
    orow[r * HDIM] = v > 0.f ? v : expm1f(v);
  }
}

// ---------------------------------------------------------------------------
extern "C" void kernel_launch(void* const* d_in, const int* in_sizes, int n_in,
                              void* d_out, int out_size, void* d_ws, size_t ws_size,
                              hipStream_t stream) {
  const float* x    = (const float*)d_in[0];
  const float* hea  = (const float*)d_in[1];
  const int*  nidx  = (const int*)d_in[2];
  const int*  eidx  = (const int*)d_in[3];
  // d_in[4], d_in[5] = node_types / hyperedge_types: unused by reference
  const float* W_lin = (const float*)d_in[6];
  const float* b_lin = (const float*)d_in[7];
  const float* ln_g  = (const float*)d_in[8];
  const float* ln_b  = (const float*)d_in[9];
  const float* W_sh  = (const float*)d_in[10];
  const float* b_sh  = (const float*)d_in[11];
  const float* W_c0  = (const float*)d_in[12];
  const float* b_c0  = (const float*)d_in[13];
  const float* W_c1  = (const float*)d_in[14];
  const float* b_c1  = (const float*)d_in[15];
  float* out = (float*)d_out;

  // workspace layout (f32), 256B aligned. Total ~103 MB.
  char* ws = (char*)d_ws;
  size_t off = 0;
  auto alloc = [&](size_t bytes) {
    size_t o = off;
    off = (off + bytes + 255) & ~(size_t)255;
    return o;
  };
  size_t o_xl0   = alloc((size_t)NROWS * HDIM * 4);               // 76.8 MB
  size_t o_msum  = alloc((size_t)EROWS * HDIM * 4);               // 15.36 MB
  size_t o_alpha = alloc((size_t)NNZV * DSTALK * 4);              // 6 MB
  size_t o_stats = alloc((size_t)(N_NODES + N_EDGES) * 8 * 4);    // 1.92 MB
  size_t o_jlN   = alloc((size_t)NNZV * 4);                       // 1 MB
  size_t o_jlE   = alloc((size_t)NNZV * 4);                       // 1 MB
  size_t o_cntN  = alloc((size_t)N_NODES * 4);
  size_t o_cntE  = alloc((size_t)N_EDGES * 4);
  size_t o_rowN  = alloc((size_t)(N_NODES + 1) * 4);
  size_t o_rowE  = alloc((size_t)(N_EDGES + 1) * 4);
  size_t o_filN  = alloc((size_t)N_NODES * 4);
  size_t o_filE  = alloc((size_t)N_EDGES * 4);
  size_t o_Dinv  = alloc((size_t)N_NODES * 4);
  size_t o_Binv  = alloc((size_t)N_EDGES * 4);
  size_t o_Weff  = alloc((size_t)IN_CH * HD * 4);                 // 196 KB
  size_t o_Wm    = alloc((size_t)IN_CH * HDIM * 4);               // 32 KB
  size_t o_cm    = alloc((size_t)HDIM * 4);
  size_t o_c0    = alloc((size_t)HD * 4);
  size_t o_gwN   = alloc((size_t)64 * DSTALK * 4);
  size_t o_gwE   = alloc((size_t)64 * DSTALK * 4);
  size_t o_G     = alloc((size_t)DSTALK * 4);
  size_t o_K     = alloc((size_t)DSTALK * 4);

  float* xl0   = (float*)(ws + o_xl0);
  float* msum  = (float*)(ws + o_msum);
  float* alpha = (float*)(ws + o_alpha);
  float* stats = (float*)(ws + o_stats);
  int*   jlN   = (int*)(ws + o_jlN);
  int*   jlE   = (int*)(ws + o_jlE);
  int*   cntN  = (int*)(ws + o_cntN);
  int*   cntE  = (int*)(ws + o_cntE);
  int*   rowN  = (int*)(ws + o_rowN);
  int*   rowE  = (int*)(ws + o_rowE);
  int*   filN  = (int*)(ws + o_filN);
  int*   filE  = (int*)(ws + o_filE);
  float* Dinv  = (float*)(ws + o_Dinv);
  float* Binv  = (float*)(ws + o_Binv);
  float* W0eff = (float*)(ws + o_Weff);
  float* Wm    = (float*)(ws + o_Wm);
  float* cm    = (float*)(ws + o_cm);
  float* c0    = (float*)(ws + o_c0);
  float* gwN   = (float*)(ws + o_gwN);
  float* gwE   = (float*)(ws + o_gwE);
  float* G     = (float*)(ws + o_G);
  float* K     = (float*)(ws + o_K);

  // 0. weight prep (incl. closed-form sheaf tables)
  k_weff<<<(IN_CH * HD + 255) / 256, 256, 0, stream>>>(W_lin, W_c0, W0eff);
  k_wsmall<<<(WS_BASE + 780 + 255) / 256, 256, 0, stream>>>(
      W_lin, b_lin, W_c0, ln_g, ln_b, W_sh, b_sh,
      Wm, cm, c0, gwN, gwE, G, K);

  // 1. CSR build: counts -> scans (+Dinv/Binv) -> fill
  hipMemsetAsync(ws + o_cntN, 0, (size_t)N_NODES * 4, stream);
  hipMemsetAsync(ws + o_cntE, 0, (size_t)N_EDGES * 4, stream);
  k_count<<<(NNZV + 255) / 256, 256, 0, stream>>>(nidx, eidx, cntN, cntE);
  k_scan<<<1, 256, 0, stream>>>(cntN, N_NODES, rowN, filN, Dinv);
  k_scan<<<1, 256, 0, stream>>>(cntE, N_EDGES, rowE, filE, Binv);
  k_fill<<<(NNZV + 255) / 256, 256, 0, stream>>>(nidx, eidx, filN, filE, jlN, jlE);

  // 2. fused stalk-mean + LN sufficient stats
  k_xa_stats<<<(N_NODES + N_EDGES + 63) / 64, 256, 0, stream>>>(
      x, hea, Wm, cm, gwN, gwE, stats);

  // 3. closed-form sheaf coefficients alpha [NNZ x 6]
  k_sheaf2<<<(NNZV + 255) / 256, 256, 0, stream>>>(nidx, eidx, stats, G, K, alpha);

  // 4. conv0: xl0 = xs@W0 (fused via W0eff); gather-diffusion; bias+ELU fused
  k_xl0<<<N_NODES / 16, 384, 0, stream>>>(x, W0eff, c0, xl0);
  k_gather_e<<<(N_EDGES + 3) / 4, 256, 0, stream>>>(rowE, jlE, nidx, alpha, xl0, Binv, msum);
  k_gather_n<<<(N_NODES + 3) / 4, 256, 0, stream>>>(rowN, jlN, eidx, alpha, msum, Dinv,
                                                    xl0, b_c0, xl0);  // xl0 now holds h1

  // 5. conv1: xl1 = h1@W1 (in place); gather-diffusion; bias+ELU into d_out
  k_xw<<<NROWS / 16, 256, 0, stream>>>(xl0, W_c1, xl0);
  k_gather_e<<<(N_EDGES + 3) / 4, 256, 0, stream>>>(rowE, jlE, nidx, alpha, xl0, Binv, msum);
  k_gather_n<<<(N_NODES + 3) / 4, 256, 0, stream>>>(rowN, jlN, eidx, alpha, msum, Dinv,
                                                    xl0, b_c1, out);

  (void)in_sizes; (void)n_in; (void)out_size; (void)ws_size;
}

// Round 5
// 753.923 us; speedup vs baseline: 2.4756x; 1.2258x over previous
//
#include <hip/hip_runtime.h>
#include <hip/hip_bf16.h>

// Problem constants (from reference)
#define N_NODES 50000
#define N_EDGES 10000
#define NNZV    250000
#define IN_CH   128
#define HDIM    64
#define DSTALK  6
#define HD      384   // HDIM * DSTALK
#define NROWS   (N_NODES * DSTALK)   // 300000
#define EROWS   (N_EDGES * DSTALK)   // 60000

// ---------------------------------------------------------------------------
// W-prep 1: W0eff[k][j=r*64+h] = sum_m W_lin[k][r*64+m] * W0[m][h]
__global__ __launch_bounds__(256) void k_weff(
    const float* __restrict__ W_lin, const float* __restrict__ W0,
    float* __restrict__ W0eff) {
  int idx = blockIdx.x * blockDim.x + threadIdx.x;
  if (idx >= IN_CH * HD) return;
  int k = idx / HD, j = idx - k * HD;
  int r = j >> 6, h = j & 63;
  float s = 0.f;
#pragma unroll 8
  for (int m = 0; m < HDIM; m++)
    s += W_lin[k * HD + r * HDIM + m] * W0[m * HDIM + h];
  W0eff[idx] = s;
}

// W-prep 2: Wm, cm, c0  +  sheaf-closed-form tables gwN, gwE, G, K
#define WS_BASE (IN_CH * HDIM + HD + HDIM)   // 8640
__global__ __launch_bounds__(256) void k_wsmall(
    const float* __restrict__ W_lin, const float* __restrict__ b_lin,
    const float* __restrict__ W0,
    const float* __restrict__ g, const float* __restrict__ bln,
    const float* __restrict__ Ws, const float* __restrict__ bs,
    float* __restrict__ Wm, float* __restrict__ cm, float* __restrict__ c0,
    float* __restrict__ gwN, float* __restrict__ gwE,
    float* __restrict__ G, float* __restrict__ K) {
  int idx = blockIdx.x * blockDim.x + threadIdx.x;
  if (idx < IN_CH * HDIM) {            // Wm
    int k = idx >> 6, h = idx & 63;
    float s = 0.f;
#pragma unroll
    for (int r = 0; r < DSTALK; r++) s += W_lin[k * HD + r * HDIM + h];
    Wm[idx] = s * (1.f / 6.f);
  } else if (idx < IN_CH * HDIM + HD) {  // c0
    int j = idx - IN_CH * HDIM;
    int r = j >> 6, h = j & 63;
    float s = 0.f;
#pragma unroll 8
    for (int m = 0; m < HDIM; m++) s += b_lin[r * HDIM + m] * W0[m * HDIM + h];
    c0[j] = s;
  } else if (idx < WS_BASE) {  // cm
    int h = idx - IN_CH * HDIM - HD;
    float s = 0.f;
#pragma unroll
    for (int r = 0; r < DSTALK; r++) s += b_lin[r * HDIM + h];
    cm[h] = s * (1.f / 6.f);
  } else if (idx < WS_BASE + 384) {      // gwN
    int i = idx - WS_BASE;
    int h = i / 6, r = i - h * 6;
    gwN[i] = g[h] * Ws[h * DSTALK + r];
  } else if (idx < WS_BASE + 768) {      // gwE
    int i = idx - WS_BASE - 384;
    int h = i / 6, r = i - h * 6;
    gwE[i] = g[64 + h] * Ws[(64 + h) * DSTALK + r];
  } else if (idx < WS_BASE + 774) {      // G
    int r = idx - WS_BASE - 768;
    float s = 0.f;
    for (int i = 0; i < 2 * HDIM; i++) s += g[i] * Ws[i * DSTALK + r];
    G[r] = s;
  } else if (idx < WS_BASE + 780) {      // K
    int r = idx - WS_BASE - 774;
    float s = 0.f;
    for (int i = 0; i < 2 * HDIM; i++) s += bln[i] * Ws[i * DSTALK + r];
    K[r] = s + bs[r];
  }
}

// ---------------------------------------------------------------------------
// Fused: row features xa = [x;hea]@Wm + cm (LDS only) -> per-row stats
__global__ __launch_bounds__(256) void k_xa_stats(
    const float* __restrict__ x, const float* __restrict__ ea,
    const float* __restrict__ Wm, const float* __restrict__ cm,
    const float* __restrict__ gwN, const float* __restrict__ gwE,
    float* __restrict__ stats) {
  __shared__ float lx[64][IN_CH];      // 32 KB input tile
  __shared__ float ox[64][HDIM + 1];   // 16.6 KB feature tile (padded)
  __shared__ float lgw[2][64 * DSTALK];
  const int row0 = blockIdx.x * 64;
  const int tid = threadIdx.x;
  for (int i = tid; i < 2 * 64 * DSTALK; i += 256) {
    int which = i / 384, k = i - which * 384;
    lgw[which][k] = which ? gwE[k] : gwN[k];
  }
  for (int i = tid; i < 64 * IN_CH; i += 256) {
    int r = i >> 7, k = i & 127;
    int row = row0 + r;
    float v = 0.f;
    if (row < N_NODES) v = x[row * IN_CH + k];
    else if (row < N_NODES + N_EDGES) v = ea[(row - N_NODES) * IN_CH + k];
    lx[r][k] = v;
  }
  __syncthreads();
  const int col = tid & 63, rg = tid >> 6;  // 4 groups x 16 rows
  float acc[16];
#pragma unroll
  for (int i = 0; i < 16; i++) acc[i] = 0.f;
  for (int k = 0; k < IN_CH; k++) {
    float w = Wm[k * HDIM + col];
#pragma unroll
    for (int i = 0; i < 16; i++) acc[i] += lx[rg * 16 + i][k] * w;
  }
  const float c = cm[col];
#pragma unroll
  for (int i = 0; i < 16; i++) ox[rg * 16 + i][col] = acc[i] + c;
  __syncthreads();
  // 512 reduction tasks: (row, stat). stat: 0=s1, 1=s2, 2..7=p[r]
  for (int t = tid; t < 512; t += 256) {
    int row = t >> 3, st = t & 7;
    int grow = row0 + row;
    if (grow >= N_NODES + N_EDGES) continue;
    const float* __restrict__ gw = (grow >= N_NODES) ? lgw[1] : lgw[0];
    float s = 0.f;
    if (st == 0) {
#pragma unroll 8
      for (int h = 0; h < HDIM; h++) s += ox[row][h];
    } else if (st == 1) {
#pragma unroll 8
      for (int h = 0; h < HDIM; h++) { float v = ox[row][h]; s += v * v; }
    } else {
      int r = st - 2;
#pragma unroll 8
      for (int h = 0; h < HDIM; h++) s += ox[row][h] * gw[h * DSTALK + r];
    }
    stats[(size_t)grow * 8 + st] = s;
  }
}

// ---------------------------------------------------------------------------
// xl0[n*384 + j] = sum_k x[n][k] * W0eff[k][j] + c0[j]   (this IS xs@W0)
__global__ __launch_bounds__(384) void k_xl0(
    const float* __restrict__ x, const float* __restrict__ W0eff,
    const float* __restrict__ c0, float* __restrict__ xl0) {
  __shared__ float lx[16][IN_CH];
  const int row0 = blockIdx.x * 16;
  const int tid = threadIdx.x;
  for (int i = tid; i < 16 * IN_CH; i += 384) {
    int r = i >> 7, k = i & 127;
    int row = row0 + r;
    lx[r][k] = (row < N_NODES) ? x[row * IN_CH + k] : 0.f;
  }
  __syncthreads();
  const int j = tid;  // 0..383
  float acc[16];
#pragma unroll
  for (int r = 0; r < 16; r++) acc[r] = 0.f;
  for (int k = 0; k < IN_CH; k++) {
    float w = W0eff[k * HD + j];
#pragma unroll
    for (int r = 0; r < 16; r++) acc[r] += lx[r][k] * w;
  }
  const float bb = c0[j];
#pragma unroll
  for (int r = 0; r < 16; r++) {
    int row = row0 + r;
    if (row < N_NODES) xl0[(size_t)row * HD + j] = acc[r] + bb;
  }
}

// ---------------------------------------------------------------------------
// closed-form sheaf coefficients: one THREAD per incidence
__global__ __launch_bounds__(256) void k_sheaf2(
    const int* __restrict__ nidx, const int* __restrict__ eidx,
    const float* __restrict__ stats,
    const float* __restrict__ G, const float* __restrict__ K,
    float* __restrict__ alpha) {
  int j = blockIdx.x * blockDim.x + threadIdx.x;
  if (j >= NNZV) return;
  int n = nidx[j], e = eidx[j];
  const float4* __restrict__ sn = (const float4*)(stats + (size_t)n * 8);
  const float4* __restrict__ se = (const float4*)(stats + ((size_t)(N_NODES + e)) * 8);
  float4 a0 = sn[0], a1 = sn[1];
  float4 b0 = se[0], b1 = se[1];
  float mu = (a0.x + b0.x) * (1.f / 128.f);
  float var = (a0.y + b0.y) * (1.f / 128.f) - mu * mu;
  float rs = rsqrtf(var + 1e-5f);
  float p[DSTALK] = {a0.z + b0.z, a0.w + b0.w, a1.x + b1.x,
                     a1.y + b1.y, a1.z + b1.z, a1.w + b1.w};
#pragma unroll
  for (int r = 0; r < DSTALK; r++) {
    float z = rs * (p[r] - mu * G[r]) + K[r];
    alpha[(size_t)j * DSTALK + r] = 1.f / (1.f + expf(-z));
  }
}

// ---------------------------------------------------------------------------
// degree counts
__global__ void k_count(const int* __restrict__ nidx, const int* __restrict__ eidx,
                        int* __restrict__ cntN, int* __restrict__ cntE) {
  int j = blockIdx.x * blockDim.x + threadIdx.x;
  if (j < NNZV) {
    atomicAdd(&cntN[nidx[j]], 1);
    atomicAdd(&cntE[eidx[j]], 1);
  }
}

// ---------------------------------------------------------------------------
// Multi-block exclusive scan, 512 elements/block.
// Phase A: block-local exclusive prefixes -> row, block totals -> bsum
__global__ __launch_bounds__(256) void k_scan_a(
    const int* __restrict__ cnt, int n, int* __restrict__ row,
    int* __restrict__ bsum) {
  const int b = blockIdx.x, t = threadIdx.x;
  const int i0 = b * 512 + 2 * t, i1 = i0 + 1;
  int c0 = (i0 < n) ? cnt[i0] : 0;
  int c1 = (i1 < n) ? cnt[i1] : 0;
  int ts = c0 + c1;
  const int lane = t & 63, wv = t >> 6;
  int s = ts;
#pragma unroll
  for (int o = 1; o < 64; o <<= 1) {
    int v = __shfl_up(s, o);
    if (lane >= o) s += v;
  }
  __shared__ int wsum[4];
  if (lane == 63) wsum[wv] = s;
  __syncthreads();
  int wbase = 0;
#pragma unroll
  for (int wprev = 0; wprev < 3; wprev++)
    if (wprev < wv) wbase += wsum[wprev];
  const int incl = wbase + s;
  const int excl = incl - ts;
  if (i0 < n) row[i0] = excl;
  if (i1 < n) row[i1] = excl + c0;
  if (t == 255) bsum[b] = incl;
}

// Phase B: scan block totals (nb <= 128) -> exclusive bases + grand total
__global__ __launch_bounds__(128) void k_scan_b(
    const int* __restrict__ bsum, int nb, int* __restrict__ bbase) {
  const int t = threadIdx.x;
  int v = (t < nb) ? bsum[t] : 0;
  const int lane = t & 63, wv = t >> 6;
  int s = v;
#pragma unroll
  for (int o = 1; o < 64; o <<= 1) {
    int u = __shfl_up(s, o);
    if (lane >= o) s += u;
  }
  __shared__ int wsum[2];
  if (lane == 63) wsum[wv] = s;
  __syncthreads();
  const int incl = ((wv == 1) ? wsum[0] : 0) + s;
  if (t < nb) bbase[t] = incl - v;
  if (t == 127) bbase[nb] = incl;
}

// Phase C: add bases in place, produce fill copy, inverse counts, sentinel
__global__ __launch_bounds__(256) void k_scan_c(
    const int* __restrict__ cnt, const int* __restrict__ bbase, int n, int nb,
    int* __restrict__ row, int* __restrict__ fill, float* __restrict__ inv) {
  int i = blockIdx.x * blockDim.x + threadIdx.x;
  if (i < n) {
    int v = row[i] + bbase[i >> 9];
    row[i] = v;
    fill[i] = v;
    int c = cnt[i];
    inv[i] = c > 0 ? 1.f / (float)c : 0.f;
  }
  if (i == 0) row[n] = bbase[nb];
}

// fill CSR incidence lists (order within a segment is arbitrary)
__global__ void k_fill(const int* __restrict__ nidx, const int* __restrict__ eidx,
                       int* __restrict__ fillN, int* __restrict__ fillE,
                       int* __restrict__ jlN, int* __restrict__ jlE) {
  int j = blockIdx.x * blockDim.x + threadIdx.x;
  if (j < NNZV) {
    int p = atomicAdd(&fillN[nidx[j]], 1);
    jlN[p] = j;
    int q = atomicAdd(&fillE[eidx[j]], 1);
    jlE[q] = j;
  }
}

// ---------------------------------------------------------------------------
// conv1 GEMM: xl = xin @ W (rows=300000). Row-local => safe in-place.
__global__ __launch_bounds__(256) void k_xw(const float* __restrict__ xin,
                                            const float* __restrict__ W,
                                            float* __restrict__ xl) {
  __shared__ float lw[64][64];
  __shared__ float lx[16][64];
  const int tid = threadIdx.x;
  for (int i = tid; i < 64 * 64; i += 256) lw[i >> 6][i & 63] = W[i];
  const int row0 = blockIdx.x * 16;
  for (int i = tid; i < 16 * 64; i += 256)
    lx[i >> 6][i & 63] = xin[(size_t)(row0 + (i >> 6)) * HDIM + (i & 63)];
  __syncthreads();
  const int c = tid & 63, rg = tid >> 6;
  float acc[4];
#pragma unroll
  for (int rr = 0; rr < 4; rr++) acc[rr] = 0.f;
  for (int k = 0; k < 64; k++) {
    float w = lw[k][c];
#pragma unroll
    for (int rr = 0; rr < 4; rr++) acc[rr] += lx[rg * 4 + rr][k] * w;
  }
  __syncthreads();  // in-place safety
#pragma unroll
  for (int rr = 0; rr < 4; rr++)
    xl[(size_t)(row0 + rg * 4 + rr) * HDIM + c] = acc[rr];
}

// ---------------------------------------------------------------------------
// gather to edges: one wave per edge
__global__ __launch_bounds__(256) void k_gather_e(
    const int* __restrict__ rowE, const int* __restrict__ jlE,
    const int* __restrict__ nidx, const float* __restrict__ alpha,
    const float* __restrict__ xl, const float* __restrict__ Binv,
    float* __restrict__ msum) {
  int e = (blockIdx.x * blockDim.x + threadIdx.x) >> 6;
  int lane = threadIdx.x & 63;
  if (e >= N_EDGES) return;
  float acc[DSTALK];
#pragma unroll
  for (int r = 0; r < DSTALK; r++) acc[r] = 0.f;
  const int lo = rowE[e], hi = rowE[e + 1];
  for (int p = lo; p < hi; p++) {
    const int j = jlE[p];
    const int n = nidx[j];
    const float* __restrict__ xr = xl + (size_t)n * HD + lane;
    const float* __restrict__ ar = alpha + (size_t)j * DSTALK;
#pragma unroll
    for (int r = 0; r < DSTALK; r++) acc[r] += ar[r] * xr[r * HDIM];
  }
  const float bv = Binv[e];
  float* __restrict__ mr = msum + (size_t)e * HD + lane;
#pragma unroll
  for (int r = 0; r < DSTALK; r++) mr[r * HDIM] = acc[r] * bv;
}

// gather back to nodes + bias + ELU epilogue: one wave per node
__global__ __launch_bounds__(256) void k_gather_n(
    const int* __restrict__ rowN, const int* __restrict__ jlN,
    const int* __restrict__ eidx, const float* __restrict__ alpha,
    const float* __restrict__ msum, const float* __restrict__ Dinv,
    const float* __restrict__ xl, const float* __restrict__ bias,
    float* __restrict__ outp) {
  int n = (blockIdx.x * blockDim.x + threadIdx.x) >> 6;
  int lane = threadIdx.x & 63;
  if (n >= N_NODES) return;
  float acc[DSTALK];
#pragma unroll
  for (int r = 0; r < DSTALK; r++) acc[r] = 0.f;
  const int lo = rowN[n], hi = rowN[n + 1];
  for (int p = lo; p < hi; p++) {
    const int j = jlN[p];
    const int e = eidx[j];
    const float* __restrict__ mr = msum + (size_t)e * HD + lane;
    const float* __restrict__ ar = alpha + (size_t)j * DSTALK;
#pragma unroll
    for (int r = 0; r < DSTALK; r++) acc[r] += ar[r] * mr[r * HDIM];
  }
  const float dv = Dinv[n];
  const float bb = bias[lane];
  const float* __restrict__ xr = xl + (size_t)n * HD + lane;
  float* __restrict__ orow = outp + (size_t)n * HD + lane;
#pragma unroll
  for (int r = 0; r < DSTALK; r++) {
    float v = xr[r * HDIM] + bb - dv * acc[r];
    orow[r * HDIM] = v > 0.f ? v : expm1f(v);
  }
}

// ---------------------------------------------------------------------------
extern "C" void kernel_launch(void* const* d_in, const int* in_sizes, int n_in,
                              void* d_out, int out_size, void* d_ws, size_t ws_size,
                              hipStream_t stream) {
  const float* x    = (const float*)d_in[0];
  const float* hea  = (const float*)d_in[1];
  const int*  nidx  = (const int*)d_in[2];
  const int*  eidx  = (const int*)d_in[3];
  // d_in[4], d_in[5] = node_types / hyperedge_types: unused by reference
  const float* W_lin = (const float*)d_in[6];
  const float* b_lin = (const float*)d_in[7];
  const float* ln_g  = (const float*)d_in[8];
  const float* ln_b  = (const float*)d_in[9];
  const float* W_sh  = (const float*)d_in[10];
  const float* b_sh  = (const float*)d_in[11];
  const float* W_c0  = (const float*)d_in[12];
  const float* b_c0  = (const float*)d_in[13];
  const float* W_c1  = (const float*)d_in[14];
  const float* b_c1  = (const float*)d_in[15];
  float* out = (float*)d_out;

  // workspace layout (f32), 256B aligned. Total ~103 MB.
  char* ws = (char*)d_ws;
  size_t off = 0;
  auto alloc = [&](size_t bytes) {
    size_t o = off;
    off = (off + bytes + 255) & ~(size_t)255;
    return o;
  };
  size_t o_xl0   = alloc((size_t)NROWS * HDIM * 4);               // 76.8 MB
  size_t o_msum  = alloc((size_t)EROWS * HDIM * 4);               // 15.36 MB
  size_t o_alpha = alloc((size_t)NNZV * DSTALK * 4);              // 6 MB
  size_t o_stats = alloc((size_t)(N_NODES + N_EDGES) * 8 * 4);    // 1.92 MB
  size_t o_jlN   = alloc((size_t)NNZV * 4);                       // 1 MB
  size_t o_jlE   = alloc((size_t)NNZV * 4);                       // 1 MB
  size_t o_cntN  = alloc((size_t)N_NODES * 4);
  size_t o_cntE  = alloc((size_t)N_EDGES * 4);
  size_t o_rowN  = alloc((size_t)(N_NODES + 1) * 4);
  size_t o_rowE  = alloc((size_t)(N_EDGES + 1) * 4);
  size_t o_filN  = alloc((size_t)N_NODES * 4);
  size_t o_filE  = alloc((size_t)N_EDGES * 4);
  size_t o_Dinv  = alloc((size_t)N_NODES * 4);
  size_t o_Binv  = alloc((size_t)N_EDGES * 4);
  size_t o_bsN   = alloc((size_t)256 * 4);
  size_t o_bbN   = alloc((size_t)256 * 4);
  size_t o_bsE   = alloc((size_t)256 * 4);
  size_t o_bbE   = alloc((size_t)256 * 4);
  size_t o_Weff  = alloc((size_t)IN_CH * HD * 4);                 // 196 KB
  size_t o_Wm    = alloc((size_t)IN_CH * HDIM * 4);               // 32 KB
  size_t o_cm    = alloc((size_t)HDIM * 4);
  size_t o_c0    = alloc((size_t)HD * 4);
  size_t o_gwN   = alloc((size_t)64 * DSTALK * 4);
  size_t o_gwE   = alloc((size_t)64 * DSTALK * 4);
  size_t o_G     = alloc((size_t)DSTALK * 4);
  size_t o_K     = alloc((size_t)DSTALK * 4);

  float* xl0   = (float*)(ws + o_xl0);
  float* msum  = (float*)(ws + o_msum);
  float* alpha = (float*)(ws + o_alpha);
  float* stats = (float*)(ws + o_stats);
  int*   jlN   = (int*)(ws + o_jlN);
  int*   jlE   = (int*)(ws + o_jlE);
  int*   cntN  = (int*)(ws + o_cntN);
  int*   cntE  = (int*)(ws + o_cntE);
  int*   rowN  = (int*)(ws + o_rowN);
  int*   rowE  = (int*)(ws + o_rowE);
  int*   filN  = (int*)(ws + o_filN);
  int*   filE  = (int*)(ws + o_filE);
  float* Dinv  = (float*)(ws + o_Dinv);
  float* Binv  = (float*)(ws + o_Binv);
  int*   bsN   = (int*)(ws + o_bsN);
  int*   bbN   = (int*)(ws + o_bbN);
  int*   bsE   = (int*)(ws + o_bsE);
  int*   bbE   = (int*)(ws + o_bbE);
  float* W0eff = (float*)(ws + o_Weff);
  float* Wm    = (float*)(ws + o_Wm);
  float* cm    = (float*)(ws + o_cm);
  float* c0    = (float*)(ws + o_c0);
  float* gwN   = (float*)(ws + o_gwN);
  float* gwE   = (float*)(ws + o_gwE);
  float* G     = (float*)(ws + o_G);
  float* K     = (float*)(ws + o_K);

  const int NB_N = (N_NODES + 511) / 512;  // 98
  const int NB_E = (N_EDGES + 511) / 512;  // 20

  // 0. weight prep (incl. closed-form sheaf tables)
  k_weff<<<(IN_CH * HD + 255) / 256, 256, 0, stream>>>(W_lin, W_c0, W0eff);
  k_wsmall<<<(WS_BASE + 780 + 255) / 256, 256, 0, stream>>>(
      W_lin, b_lin, W_c0, ln_g, ln_b, W_sh, b_sh,
      Wm, cm, c0, gwN, gwE, G, K);

  // 1. CSR build: counts -> parallel scans (+Dinv/Binv) -> fill
  hipMemsetAsync(ws + o_cntN, 0, (size_t)N_NODES * 4, stream);
  hipMemsetAsync(ws + o_cntE, 0, (size_t)N_EDGES * 4, stream);
  k_count<<<(NNZV + 255) / 256, 256, 0, stream>>>(nidx, eidx, cntN, cntE);
  k_scan_a<<<NB_N, 256, 0, stream>>>(cntN, N_NODES, rowN, bsN);
  k_scan_a<<<NB_E, 256, 0, stream>>>(cntE, N_EDGES, rowE, bsE);
  k_scan_b<<<1, 128, 0, stream>>>(bsN, NB_N, bbN);
  k_scan_b<<<1, 128, 0, stream>>>(bsE, NB_E, bbE);
  k_scan_c<<<(N_NODES + 255) / 256, 256, 0, stream>>>(cntN, bbN, N_NODES, NB_N,
                                                      rowN, filN, Dinv);
  k_scan_c<<<(N_EDGES + 255) / 256, 256, 0, stream>>>(cntE, bbE, N_EDGES, NB_E,
                                                      rowE, filE, Binv);
  k_fill<<<(NNZV + 255) / 256, 256, 0, stream>>>(nidx, eidx, filN, filE, jlN, jlE);

  // 2. fused stalk-mean + LN sufficient stats
  k_xa_stats<<<(N_NODES + N_EDGES + 63) / 64, 256, 0, stream>>>(
      x, hea, Wm, cm, gwN, gwE, stats);

  // 3. closed-form sheaf coefficients alpha [NNZ x 6]
  k_sheaf2<<<(NNZV + 255) / 256, 256, 0, stream>>>(nidx, eidx, stats, G, K, alpha);

  // 4. conv0: xl0 = xs@W0 (fused via W0eff); gather-diffusion; bias+ELU fused
  k_xl0<<<N_NODES / 16, 384, 0, stream>>>(x, W0eff, c0, xl0);
  k_gather_e<<<(N_EDGES + 3) / 4, 256, 0, stream>>>(rowE, jlE, nidx, alpha, xl0, Binv, msum);
  k_gather_n<<<(N_NODES + 3) / 4, 256, 0, stream>>>(rowN, jlN, eidx, alpha, msum, Dinv,
                                                    xl0, b_c0, xl0);  // xl0 now holds h1

  // 5. conv1: xl1 = h1@W1 (in place); gather-diffusion; bias+ELU into d_out
  k_xw<<<NROWS / 16, 256, 0, stream>>>(xl0, W_c1, xl0);
  k_gather_e<<<(N_EDGES + 3) / 4, 256, 0, stream>>>(rowE, jlE, nidx, alpha, xl0, Binv, msum);
  k_gather_n<<<(N_NODES + 3) / 4, 256, 0, stream>>>(rowN, jlN, eidx, alpha, msum, Dinv,
                                                    xl0, b_c1, out);

  (void)in_sizes; (void)n_in; (void)out_size; (void)ws_size;
}

// Round 6
// 672.956 us; speedup vs baseline: 2.7735x; 1.1203x over previous
//
#include <hip/hip_runtime.h>
#include <hip/hip_bf16.h>

// Problem constants (from reference)
#define N_NODES 50000
#define N_EDGES 10000
#define NNZV    250000
#define IN_CH   128
#define HDIM    64
#define DSTALK  6
#define HD      384   // HDIM * DSTALK
#define NROWS   (N_NODES * DSTALK)   // 300000
#define EROWS   (N_EDGES * DSTALK)   // 60000

// ---------------------------------------------------------------------------
// W-prep 1: W0effT[j][k] = sum_m W_lin[k][r*64+m] * W0[m][h]  (j=r*64+h)
// transposed [384][128] so the GEMM can vector-load along k.
__global__ __launch_bounds__(256) void k_wefft(
    const float* __restrict__ W_lin, const float* __restrict__ W0,
    float* __restrict__ W0effT) {
  int idx = blockIdx.x * blockDim.x + threadIdx.x;
  if (idx >= IN_CH * HD) return;
  int k = idx / HD, j = idx - k * HD;
  int r = j >> 6, h = j & 63;
  float s = 0.f;
#pragma unroll 8
  for (int m = 0; m < HDIM; m++)
    s += W_lin[k * HD + r * HDIM + m] * W0[m * HDIM + h];
  W0effT[(size_t)j * IN_CH + k] = s;
}

// W-prep 2: Wm, cm, c0 + sheaf tables gwN/gwE/G/K + W1T transpose
#define WS_BASE (IN_CH * HDIM + HD + HDIM)   // 8640
#define WS_END  (WS_BASE + 780 + HDIM * HDIM)
__global__ __launch_bounds__(256) void k_wsmall(
    const float* __restrict__ W_lin, const float* __restrict__ b_lin,
    const float* __restrict__ W0, const float* __restrict__ W1,
    const float* __restrict__ g, const float* __restrict__ bln,
    const float* __restrict__ Ws, const float* __restrict__ bs,
    float* __restrict__ Wm, float* __restrict__ cm, float* __restrict__ c0,
    float* __restrict__ gwN, float* __restrict__ gwE,
    float* __restrict__ G, float* __restrict__ K, float* __restrict__ W1T) {
  int idx = blockIdx.x * blockDim.x + threadIdx.x;
  if (idx < IN_CH * HDIM) {            // Wm
    int k = idx >> 6, h = idx & 63;
    float s = 0.f;
#pragma unroll
    for (int r = 0; r < DSTALK; r++) s += W_lin[k * HD + r * HDIM + h];
    Wm[idx] = s * (1.f / 6.f);
  } else if (idx < IN_CH * HDIM + HD) {  // c0
    int j = idx - IN_CH * HDIM;
    int r = j >> 6, h = j & 63;
    float s = 0.f;
#pragma unroll 8
    for (int m = 0; m < HDIM; m++) s += b_lin[r * HDIM + m] * W0[m * HDIM + h];
    c0[j] = s;
  } else if (idx < WS_BASE) {  // cm
    int h = idx - IN_CH * HDIM - HD;
    float s = 0.f;
#pragma unroll
    for (int r = 0; r < DSTALK; r++) s += b_lin[r * HDIM + h];
    cm[h] = s * (1.f / 6.f);
  } else if (idx < WS_BASE + 384) {      // gwN
    int i = idx - WS_BASE;
    int h = i / 6, r = i - h * 6;
    gwN[i] = g[h] * Ws[h * DSTALK + r];
  } else if (idx < WS_BASE + 768) {      // gwE
    int i = idx - WS_BASE - 384;
    int h = i / 6, r = i - h * 6;
    gwE[i] = g[64 + h] * Ws[(64 + h) * DSTALK + r];
  } else if (idx < WS_BASE + 774) {      // G
    int r = idx - WS_BASE - 768;
    float s = 0.f;
    for (int i = 0; i < 2 * HDIM; i++) s += g[i] * Ws[i * DSTALK + r];
    G[r] = s;
  } else if (idx < WS_BASE + 780) {      // K
    int r = idx - WS_BASE - 774;
    float s = 0.f;
    for (int i = 0; i < 2 * HDIM; i++) s += bln[i] * Ws[i * DSTALK + r];
    K[r] = s + bs[r];
  } else if (idx < WS_END) {             // W1T[c][k] = W1[k][c]
    int i = idx - WS_BASE - 780;
    int c = i >> 6, k = i & 63;
    W1T[c * HDIM + k] = W1[k * HDIM + c];
  }
}

// ---------------------------------------------------------------------------
// Fused: row features xa = [x;hea]@Wm + cm (LDS only) -> per-row stats
__global__ __launch_bounds__(256) void k_xa_stats(
    const float* __restrict__ x, const float* __restrict__ ea,
    const float* __restrict__ Wm, const float* __restrict__ cm,
    const float* __restrict__ gwN, const float* __restrict__ gwE,
    float* __restrict__ stats) {
  __shared__ float lx[64][IN_CH];      // 32 KB input tile
  __shared__ float ox[64][HDIM + 1];   // 16.6 KB feature tile (padded)
  __shared__ float lgw[2][64 * DSTALK];
  const int row0 = blockIdx.x * 64;
  const int tid = threadIdx.x;
  for (int i = tid; i < 2 * 64 * DSTALK; i += 256) {
    int which = i / 384, k = i - which * 384;
    lgw[which][k] = which ? gwE[k] : gwN[k];
  }
  for (int i = tid; i < 64 * IN_CH; i += 256) {
    int r = i >> 7, k = i & 127;
    int row = row0 + r;
    float v = 0.f;
    if (row < N_NODES) v = x[row * IN_CH + k];
    else if (row < N_NODES + N_EDGES) v = ea[(row - N_NODES) * IN_CH + k];
    lx[r][k] = v;
  }
  __syncthreads();
  const int col = tid & 63, rg = tid >> 6;  // 4 groups x 16 rows
  float acc[16];
#pragma unroll
  for (int i = 0; i < 16; i++) acc[i] = 0.f;
  for (int k = 0; k < IN_CH; k++) {
    float w = Wm[k * HDIM + col];
#pragma unroll
    for (int i = 0; i < 16; i++) acc[i] += lx[rg * 16 + i][k] * w;
  }
  const float c = cm[col];
#pragma unroll
  for (int i = 0; i < 16; i++) ox[rg * 16 + i][col] = acc[i] + c;
  __syncthreads();
  // 512 reduction tasks: (row, stat). stat: 0=s1, 1=s2, 2..7=p[r]
  for (int t = tid; t < 512; t += 256) {
    int row = t >> 3, st = t & 7;
    int grow = row0 + row;
    if (grow >= N_NODES + N_EDGES) continue;
    const float* __restrict__ gw = (grow >= N_NODES) ? lgw[1] : lgw[0];
    float s = 0.f;
    if (st == 0) {
#pragma unroll 8
      for (int h = 0; h < HDIM; h++) s += ox[row][h];
    } else if (st == 1) {
#pragma unroll 8
      for (int h = 0; h < HDIM; h++) { float v = ox[row][h]; s += v * v; }
    } else {
      int r = st - 2;
#pragma unroll 8
      for (int h = 0; h < HDIM; h++) s += ox[row][h] * gw[h * DSTALK + r];
    }
    stats[(size_t)grow * 8 + st] = s;
  }
}

// ---------------------------------------------------------------------------
// Register-tiled fp32 GEMM: xl0[row][col] = x[row][:] . W0effT[col][:] + c0
// 64x64 tile per block, 4x4 per thread (strided ownership), k-quad float4 LDS.
__global__ __launch_bounds__(256) void k_xl0(
    const float* __restrict__ x, const float* __restrict__ W0effT,
    const float* __restrict__ c0, float* __restrict__ xl0) {
  __shared__ float4 xav[16][65];   // [kq][row]
  __shared__ float4 wbv[16][65];   // [kq][col]
  const int tid = threadIdx.x;
  const int row0 = blockIdx.x * 64;
  const int col0 = blockIdx.y * 64;
  const int tc = tid & 15, tr = tid >> 4;
  float acc[4][4] = {{0.f}};
  for (int kc = 0; kc < 2; kc++) {
    if (kc) __syncthreads();
#pragma unroll
    for (int i = 0; i < 4; i++) {
      int fidx = tid + i * 256;          // 0..1023
      int row = fidx >> 4, kq = fidx & 15;
      int gk = kc * 64 + kq * 4;
      int grow = row0 + row;
      float4 v = make_float4(0.f, 0.f, 0.f, 0.f);
      if (grow < N_NODES) v = *(const float4*)(x + (size_t)grow * IN_CH + gk);
      xav[kq][row] = v;
      wbv[kq][row] = *(const float4*)(W0effT + (size_t)(col0 + row) * IN_CH + gk);
    }
    __syncthreads();
    for (int kq = 0; kq < 16; kq++) {
      float4 xa[4], wb[4];
#pragma unroll
      for (int i = 0; i < 4; i++) xa[i] = xav[kq][tr + (i << 4)];
#pragma unroll
      for (int j = 0; j < 4; j++) wb[j] = wbv[kq][tc + (j << 4)];
#pragma unroll
      for (int i = 0; i < 4; i++)
#pragma unroll
        for (int j = 0; j < 4; j++)
          acc[i][j] += xa[i].x * wb[j].x + xa[i].y * wb[j].y +
                       xa[i].z * wb[j].z + xa[i].w * wb[j].w;
    }
  }
#pragma unroll
  for (int i = 0; i < 4; i++) {
    int row = row0 + tr + (i << 4);
    if (row >= N_NODES) continue;
#pragma unroll
    for (int j = 0; j < 4; j++) {
      int col = col0 + tc + (j << 4);
      xl0[(size_t)row * HD + col] = acc[i][j] + c0[col];
    }
  }
}

// ---------------------------------------------------------------------------
// Register-tiled fp32 GEMM: xl = xin @ W1 (K=64, N=64). In-place safe.
__global__ __launch_bounds__(256) void k_xw(
    const float* __restrict__ xin, const float* __restrict__ W1T,
    float* __restrict__ xl) {
  __shared__ float4 xav[16][65];
  __shared__ float4 wbv[16][65];
  const int tid = threadIdx.x;
  const int row0 = blockIdx.x * 64;
  const int tc = tid & 15, tr = tid >> 4;
#pragma unroll
  for (int i = 0; i < 4; i++) {
    int fidx = tid + i * 256;          // 0..1023
    int row = fidx >> 4, kq = fidx & 15;
    int grow = row0 + row;
    float4 v = make_float4(0.f, 0.f, 0.f, 0.f);
    if (grow < NROWS) v = *(const float4*)(xin + (size_t)grow * HDIM + kq * 4);
    xav[kq][row] = v;
    wbv[kq][row] = *(const float4*)(W1T + row * HDIM + kq * 4);
  }
  __syncthreads();
  float acc[4][4] = {{0.f}};
  for (int kq = 0; kq < 16; kq++) {
    float4 xa[4], wb[4];
#pragma unroll
    for (int i = 0; i < 4; i++) xa[i] = xav[kq][tr + (i << 4)];
#pragma unroll
    for (int j = 0; j < 4; j++) wb[j] = wbv[kq][tc + (j << 4)];
#pragma unroll
    for (int i = 0; i < 4; i++)
#pragma unroll
      for (int j = 0; j < 4; j++)
        acc[i][j] += xa[i].x * wb[j].x + xa[i].y * wb[j].y +
                     xa[i].z * wb[j].z + xa[i].w * wb[j].w;
  }
#pragma unroll
  for (int i = 0; i < 4; i++) {
    int row = row0 + tr + (i << 4);
    if (row >= NROWS) continue;
#pragma unroll
    for (int j = 0; j < 4; j++) {
      int col = tc + (j << 4);
      xl[(size_t)row * HDIM + col] = acc[i][j];
    }
  }
}

// ---------------------------------------------------------------------------
// closed-form sheaf coefficients: one THREAD per incidence
__global__ __launch_bounds__(256) void k_sheaf2(
    const int* __restrict__ nidx, const int* __restrict__ eidx,
    const float* __restrict__ stats,
    const float* __restrict__ G, const float* __restrict__ K,
    float* __restrict__ alpha) {
  int j = blockIdx.x * blockDim.x + threadIdx.x;
  if (j >= NNZV) return;
  int n = nidx[j], e = eidx[j];
  const float4* __restrict__ sn = (const float4*)(stats + (size_t)n * 8);
  const float4* __restrict__ se = (const float4*)(stats + ((size_t)(N_NODES + e)) * 8);
  float4 a0 = sn[0], a1 = sn[1];
  float4 b0 = se[0], b1 = se[1];
  float mu = (a0.x + b0.x) * (1.f / 128.f);
  float var = (a0.y + b0.y) * (1.f / 128.f) - mu * mu;
  float rs = rsqrtf(var + 1e-5f);
  float p[DSTALK] = {a0.z + b0.z, a0.w + b0.w, a1.x + b1.x,
                     a1.y + b1.y, a1.z + b1.z, a1.w + b1.w};
#pragma unroll
  for (int r = 0; r < DSTALK; r++) {
    float z = rs * (p[r] - mu * G[r]) + K[r];
    alpha[(size_t)j * DSTALK + r] = 1.f / (1.f + expf(-z));
  }
}

// ---------------------------------------------------------------------------
// degree counts
__global__ void k_count(const int* __restrict__ nidx, const int* __restrict__ eidx,
                        int* __restrict__ cntN, int* __restrict__ cntE) {
  int j = blockIdx.x * blockDim.x + threadIdx.x;
  if (j < NNZV) {
    atomicAdd(&cntN[nidx[j]], 1);
    atomicAdd(&cntE[eidx[j]], 1);
  }
}

// ---------------------------------------------------------------------------
// Multi-block exclusive scan, 512 elements/block.
__global__ __launch_bounds__(256) void k_scan_a(
    const int* __restrict__ cnt, int n, int* __restrict__ row,
    int* __restrict__ bsum) {
  const int b = blockIdx.x, t = threadIdx.x;
  const int i0 = b * 512 + 2 * t, i1 = i0 + 1;
  int c0 = (i0 < n) ? cnt[i0] : 0;
  int c1 = (i1 < n) ? cnt[i1] : 0;
  int ts = c0 + c1;
  const int lane = t & 63, wv = t >> 6;
  int s = ts;
#pragma unroll
  for (int o = 1; o < 64; o <<= 1) {
    int v = __shfl_up(s, o);
    if (lane >= o) s += v;
  }
  __shared__ int wsum[4];
  if (lane == 63) wsum[wv] = s;
  __syncthreads();
  int wbase = 0;
#pragma unroll
  for (int wprev = 0; wprev < 3; wprev++)
    if (wprev < wv) wbase += wsum[wprev];
  const int incl = wbase + s;
  const int excl = incl - ts;
  if (i0 < n) row[i0] = excl;
  if (i1 < n) row[i1] = excl + c0;
  if (t == 255) bsum[b] = incl;
}

__global__ __launch_bounds__(128) void k_scan_b(
    const int* __restrict__ bsum, int nb, int* __restrict__ bbase) {
  const int t = threadIdx.x;
  int v = (t < nb) ? bsum[t] : 0;
  const int lane = t & 63, wv = t >> 6;
  int s = v;
#pragma unroll
  for (int o = 1; o < 64; o <<= 1) {
    int u = __shfl_up(s, o);
    if (lane >= o) s += u;
  }
  __shared__ int wsum[2];
  if (lane == 63) wsum[wv] = s;
  __syncthreads();
  const int incl = ((wv == 1) ? wsum[0] : 0) + s;
  if (t < nb) bbase[t] = incl - v;
  if (t == 127) bbase[nb] = incl;
}

__global__ __launch_bounds__(256) void k_scan_c(
    const int* __restrict__ cnt, const int* __restrict__ bbase, int n, int nb,
    int* __restrict__ row, int* __restrict__ fill, float* __restrict__ inv) {
  int i = blockIdx.x * blockDim.x + threadIdx.x;
  if (i < n) {
    int v = row[i] + bbase[i >> 9];
    row[i] = v;
    fill[i] = v;
    int c = cnt[i];
    inv[i] = c > 0 ? 1.f / (float)c : 0.f;
  }
  if (i == 0) row[n] = bbase[nb];
}

// fill CSR incidence lists + direct neighbor lists (order arbitrary)
__global__ void k_fill(const int* __restrict__ nidx, const int* __restrict__ eidx,
                       int* __restrict__ fillN, int* __restrict__ fillE,
                       int* __restrict__ jlN, int* __restrict__ jlE,
                       int* __restrict__ elN, int* __restrict__ nlE) {
  int j = blockIdx.x * blockDim.x + threadIdx.x;
  if (j < NNZV) {
    int n = nidx[j], e = eidx[j];
    int p = atomicAdd(&fillN[n], 1);
    jlN[p] = j; elN[p] = e;
    int q = atomicAdd(&fillE[e], 1);
    jlE[q] = j; nlE[q] = n;
  }
}

// ---------------------------------------------------------------------------
// gather to edges: one wave per edge
__global__ __launch_bounds__(256) void k_gather_e(
    const int* __restrict__ rowE, const int* __restrict__ jlE,
    const int* __restrict__ nlE, const float* __restrict__ alpha,
    const float* __restrict__ xl, const float* __restrict__ Binv,
    float* __restrict__ msum) {
  int e = (blockIdx.x * blockDim.x + threadIdx.x) >> 6;
  int lane = threadIdx.x & 63;
  if (e >= N_EDGES) return;
  float acc[DSTALK];
#pragma unroll
  for (int r = 0; r < DSTALK; r++) acc[r] = 0.f;
  const int lo = rowE[e], hi = rowE[e + 1];
  for (int p = lo; p < hi; p++) {
    const int j = jlE[p];
    const int n = nlE[p];
    const float* __restrict__ xr = xl + (size_t)n * HD + lane;
    const float* __restrict__ ar = alpha + (size_t)j * DSTALK;
#pragma unroll
    for (int r = 0; r < DSTALK; r++) acc[r] += ar[r] * xr[r * HDIM];
  }
  const float bv = Binv[e];
  float* __restrict__ mr = msum + (size_t)e * HD + lane;
#pragma unroll
  for (int r = 0; r < DSTALK; r++) mr[r * HDIM] = acc[r] * bv;
}

// gather back to nodes + bias + ELU epilogue: one wave per node
__global__ __launch_bounds__(256) void k_gather_n(
    const int* __restrict__ rowN, const int* __restrict__ jlN,
    const int* __restrict__ elN, const float* __restrict__ alpha,
    const float* __restrict__ msum, const float* __restrict__ Dinv,
    const float* __restrict__ xl, const float* __restrict__ bias,
    float* __restrict__ outp) {
  int n = (blockIdx.x * blockDim.x + threadIdx.x) >> 6;
  int lane = threadIdx.x & 63;
  if (n >= N_NODES) return;
  float acc[DSTALK];
#pragma unroll
  for (int r = 0; r < DSTALK; r++) acc[r] = 0.f;
  const int lo = rowN[n], hi = rowN[n + 1];
  for (int p = lo; p < hi; p++) {
    const int j = jlN[p];
    const int e = elN[p];
    const float* __restrict__ mr = msum + (size_t)e * HD + lane;
    const float* __restrict__ ar = alpha + (size_t)j * DSTALK;
#pragma unroll
    for (int r = 0; r < DSTALK; r++) acc[r] += ar[r] * mr[r * HDIM];
  }
  const float dv = Dinv[n];
  const float bb = bias[lane];
  const float* __restrict__ xr = xl + (size_t)n * HD + lane;
  float* __restrict__ orow = outp + (size_t)n * HD + lane;
#pragma unroll
  for (int r = 0; r < DSTALK; r++) {
    float v = xr[r * HDIM] + bb - dv * acc[r];
    orow[r * HDIM] = v > 0.f ? v : expm1f(v);
  }
}

// ---------------------------------------------------------------------------
extern "C" void kernel_launch(void* const* d_in, const int* in_sizes, int n_in,
                              void* d_out, int out_size, void* d_ws, size_t ws_size,
                              hipStream_t stream) {
  const float* x    = (const float*)d_in[0];
  const float* hea  = (const float*)d_in[1];
  const int*  nidx  = (const int*)d_in[2];
  const int*  eidx  = (const int*)d_in[3];
  // d_in[4], d_in[5] = node_types / hyperedge_types: unused by reference
  const float* W_lin = (const float*)d_in[6];
  const float* b_lin = (const float*)d_in[7];
  const float* ln_g  = (const float*)d_in[8];
  const float* ln_b  = (const float*)d_in[9];
  const float* W_sh  = (const float*)d_in[10];
  const float* b_sh  = (const float*)d_in[11];
  const float* W_c0  = (const float*)d_in[12];
  const float* b_c0  = (const float*)d_in[13];
  const float* W_c1  = (const float*)d_in[14];
  const float* b_c1  = (const float*)d_in[15];
  float* out = (float*)d_out;

  // workspace layout (f32), 256B aligned. Total ~105 MB.
  char* ws = (char*)d_ws;
  size_t off = 0;
  auto alloc = [&](size_t bytes) {
    size_t o = off;
    off = (off + bytes + 255) & ~(size_t)255;
    return o;
  };
  size_t o_xl0   = alloc((size_t)NROWS * HDIM * 4);               // 76.8 MB
  size_t o_msum  = alloc((size_t)EROWS * HDIM * 4);               // 15.36 MB
  size_t o_alpha = alloc((size_t)NNZV * DSTALK * 4);              // 6 MB
  size_t o_stats = alloc((size_t)(N_NODES + N_EDGES) * 8 * 4);    // 1.92 MB
  size_t o_jlN   = alloc((size_t)NNZV * 4);                       // 1 MB
  size_t o_jlE   = alloc((size_t)NNZV * 4);                       // 1 MB
  size_t o_elN   = alloc((size_t)NNZV * 4);                       // 1 MB
  size_t o_nlE   = alloc((size_t)NNZV * 4);                       // 1 MB
  size_t o_cntN  = alloc((size_t)N_NODES * 4);
  size_t o_cntE  = alloc((size_t)N_EDGES * 4);
  size_t o_rowN  = alloc((size_t)(N_NODES + 1) * 4);
  size_t o_rowE  = alloc((size_t)(N_EDGES + 1) * 4);
  size_t o_filN  = alloc((size_t)N_NODES * 4);
  size_t o_filE  = alloc((size_t)N_EDGES * 4);
  size_t o_Dinv  = alloc((size_t)N_NODES * 4);
  size_t o_Binv  = alloc((size_t)N_EDGES * 4);
  size_t o_bsN   = alloc((size_t)256 * 4);
  size_t o_bbN   = alloc((size_t)256 * 4);
  size_t o_bsE   = alloc((size_t)256 * 4);
  size_t o_bbE   = alloc((size_t)256 * 4);
  size_t o_WeffT = alloc((size_t)IN_CH * HD * 4);                 // 196 KB
  size_t o_Wm    = alloc((size_t)IN_CH * HDIM * 4);               // 32 KB
  size_t o_cm    = alloc((size_t)HDIM * 4);
  size_t o_c0    = alloc((size_t)HD * 4);
  size_t o_gwN   = alloc((size_t)64 * DSTALK * 4);
  size_t o_gwE   = alloc((size_t)64 * DSTALK * 4);
  size_t o_G     = alloc((size_t)DSTALK * 4);
  size_t o_K     = alloc((size_t)DSTALK * 4);
  size_t o_W1T   = alloc((size_t)HDIM * HDIM * 4);                // 16 KB

  float* xl0    = (float*)(ws + o_xl0);
  float* msum   = (float*)(ws + o_msum);
  float* alpha  = (float*)(ws + o_alpha);
  float* stats  = (float*)(ws + o_stats);
  int*   jlN    = (int*)(ws + o_jlN);
  int*   jlE    = (int*)(ws + o_jlE);
  int*   elN    = (int*)(ws + o_elN);
  int*   nlE    = (int*)(ws + o_nlE);
  int*   cntN   = (int*)(ws + o_cntN);
  int*   cntE   = (int*)(ws + o_cntE);
  int*   rowN   = (int*)(ws + o_rowN);
  int*   rowE   = (int*)(ws + o_rowE);
  int*   filN   = (int*)(ws + o_filN);
  int*   filE   = (int*)(ws + o_filE);
  float* Dinv   = (float*)(ws + o_Dinv);
  float* Binv   = (float*)(ws + o_Binv);
  int*   bsN    = (int*)(ws + o_bsN);
  int*   bbN    = (int*)(ws + o_bbN);
  int*   bsE    = (int*)(ws + o_bsE);
  int*   bbE    = (int*)(ws + o_bbE);
  float* W0effT = (float*)(ws + o_WeffT);
  float* Wm     = (float*)(ws + o_Wm);
  float* cm     = (float*)(ws + o_cm);
  float* c0     = (float*)(ws + o_c0);
  float* gwN    = (float*)(ws + o_gwN);
  float* gwE    = (float*)(ws + o_gwE);
  float* G      = (float*)(ws + o_G);
  float* K      = (float*)(ws + o_K);
  float* W1T    = (float*)(ws + o_W1T);

  const int NB_N = (N_NODES + 511) / 512;  // 98
  const int NB_E = (N_EDGES + 511) / 512;  // 20

  // 0. weight prep
  k_wefft<<<(IN_CH * HD + 255) / 256, 256, 0, stream>>>(W_lin, W_c0, W0effT);
  k_wsmall<<<(WS_END + 255) / 256, 256, 0, stream>>>(
      W_lin, b_lin, W_c0, W_c1, ln_g, ln_b, W_sh, b_sh,
      Wm, cm, c0, gwN, gwE, G, K, W1T);

  // 1. CSR build: counts -> parallel scans (+Dinv/Binv) -> fill
  hipMemsetAsync(ws + o_cntN, 0, (size_t)N_NODES * 4, stream);
  hipMemsetAsync(ws + o_cntE, 0, (size_t)N_EDGES * 4, stream);
  k_count<<<(NNZV + 255) / 256, 256, 0, stream>>>(nidx, eidx, cntN, cntE);
  k_scan_a<<<NB_N, 256, 0, stream>>>(cntN, N_NODES, rowN, bsN);
  k_scan_a<<<NB_E, 256, 0, stream>>>(cntE, N_EDGES, rowE, bsE);
  k_scan_b<<<1, 128, 0, stream>>>(bsN, NB_N, bbN);
  k_scan_b<<<1, 128, 0, stream>>>(bsE, NB_E, bbE);
  k_scan_c<<<(N_NODES + 255) / 256, 256, 0, stream>>>(cntN, bbN, N_NODES, NB_N,
                                                      rowN, filN, Dinv);
  k_scan_c<<<(N_EDGES + 255) / 256, 256, 0, stream>>>(cntE, bbE, N_EDGES, NB_E,
                                                      rowE, filE, Binv);
  k_fill<<<(NNZV + 255) / 256, 256, 0, stream>>>(nidx, eidx, filN, filE,
                                                 jlN, jlE, elN, nlE);

  // 2. fused stalk-mean + LN sufficient stats
  k_xa_stats<<<(N_NODES + N_EDGES + 63) / 64, 256, 0, stream>>>(
      x, hea, Wm, cm, gwN, gwE, stats);

  // 3. closed-form sheaf coefficients alpha [NNZ x 6]
  k_sheaf2<<<(NNZV + 255) / 256, 256, 0, stream>>>(nidx, eidx, stats, G, K, alpha);

  // 4. conv0: xl0 = xs@W0 (fused via W0effT); gather-diffusion; bias+ELU fused
  {
    dim3 g((N_NODES + 63) / 64, HD / 64);
    k_xl0<<<g, 256, 0, stream>>>(x, W0effT, c0, xl0);
  }
  k_gather_e<<<(N_EDGES + 3) / 4, 256, 0, stream>>>(rowE, jlE, nlE, alpha, xl0, Binv, msum);
  k_gather_n<<<(N_NODES + 3) / 4, 256, 0, stream>>>(rowN, jlN, elN, alpha, msum, Dinv,
                                                    xl0, b_c0, xl0);  // xl0 now holds h1

  // 5. conv1: xl1 = h1@W1 (in place); gather-diffusion; bias+ELU into d_out
  k_xw<<<(NROWS + 63) / 64, 256, 0, stream>>>(xl0, W1T, xl0);
  k_gather_e<<<(N_EDGES + 3) / 4, 256, 0, stream>>>(rowE, jlE, nlE, alpha, xl0, Binv, msum);
  k_gather_n<<<(N_NODES + 3) / 4, 256, 0, stream>>>(rowN, jlN, elN, alpha, msum, Dinv,
                                                    xl0, b_c1, out);

  (void)in_sizes; (void)n_in; (void)out_size; (void)ws_size;
}